// Round 16
// baseline (650.138 us; speedup 1.0000x reference)
//
#include <hip/hip_runtime.h>
#include <hip/hip_bf16.h>

#define B_ 2
#define S_ 1024
#define D_ 768
#define H_ 12
#define HD_ 64
#define V_ 32000
#define NQ_ 768
#define NTOK (B_*S_)
#define QKVS 1572864L   // shorts per Q/K/V segment [B,H,S,64]

typedef __attribute__((ext_vector_type(8))) short short8;
typedef __attribute__((ext_vector_type(4))) short s16x4;
typedef __attribute__((ext_vector_type(4))) float f32x4;
typedef __attribute__((ext_vector_type(4))) int i32x4;

typedef const __attribute__((address_space(1))) void* as1vp;
typedef __attribute__((address_space(3))) void* as3vp;

__device__ __forceinline__ short f2bf(float f) {
    union { float f; unsigned u; } v; v.f = f;
    unsigned r = (v.u + 0x7FFFu + ((v.u >> 16) & 1u)) >> 16;
    return (short)r;
}
__device__ __forceinline__ float b2fs(short s) {
    union { unsigned u; float f; } v; v.u = ((unsigned)(unsigned short)s) << 16;
    return v.f;
}

// ---------------- embedding + maxpool3 fused ----------------
__global__ void k_embed2(const int* __restrict__ x, const float* __restrict__ emb,
                         short* __restrict__ h0b, short* __restrict__ mpb) {
    int n = blockIdx.x; int s = n & (S_-1);
    int r0 = x[n];
    int rm = (s > 0)      ? x[n-1] : -1;
    int rp = (s < S_-1)   ? x[n+1] : -1;
    for (int d = threadIdx.x; d < D_; d += blockDim.x) {
        float e = emb[(long)r0*D_ + d];
        float m = e;
        if (rm >= 0) m = fmaxf(m, emb[(long)rm*D_ + d]);
        if (rp >= 0) m = fmaxf(m, emb[(long)rp*D_ + d]);
        h0b[(long)n*D_ + d] = f2bf(e);
        mpb[(long)n*D_ + d] = f2bf(m);
    }
}

// ---------------- fused conv3+conv5+copy+incp-merge+quantum x2 ----------------
__global__ __launch_bounds__(256) void k_mix(
    const float* __restrict__ CO, const float* __restrict__ c3w,
    const float* __restrict__ c3b, const float* __restrict__ c5w,
    const float* __restrict__ c5b, const float* __restrict__ q_rot,
    const float* __restrict__ q_ent, float* __restrict__ h1f)
{
    __shared__ float co[5][176];
    __shared__ float ta[NQ_];
    __shared__ float tb[NQ_];
    int n = blockIdx.x; int s = n & (S_-1);
    int t = threadIdx.x;
    for (int idx = t; idx < 5*176; idx += 256) {
        int dr = idx / 176 - 2, c = idx % 176;
        int ss = s + dr;
        co[idx/176][c] = (ss >= 0 && ss < S_) ? CO[(long)(n + dr)*176 + c] : 0.f;
    }
    for (int d = 256 + t; d < NQ_; d += 256) ta[d] = 0.f;
    __syncthreads();
    if (t < 64) {
        ta[t] = co[2][t];
    } else if (t < 192) {
        int o = t - 64;
        float acc = c3b[o];
        #pragma unroll
        for (int k = 0; k < 3; k++)
            for (int i = 0; i < 96; i++)
                acc += co[1+k][64+i] * c3w[(o*96+i)*3 + k];
        ta[t] = acc;
    } else if (t < 224) {
        int o = t - 192;
        float acc = c5b[o];
        #pragma unroll
        for (int k = 0; k < 5; k++)
            for (int i = 0; i < 16; i++)
                acc += co[k][160+i] * c5w[(o*16+i)*5 + k];
        ta[t] = acc;
    } else {
        ta[t] = h1f[(long)n*NQ_ + t];
    }
    __syncthreads();
    #pragma unroll
    for (int layer = 0; layer < 2; layer++) {
        const float* rot = q_rot + (long)layer*NQ_*3;
        const float* ent = q_ent + (long)layer*(NQ_-1);
        for (int q = t; q < NQ_; q += 256) {
            float hv = ta[q];
            tb[q] = __sinf(hv + rot[q*3]) + __sinf(hv + rot[q*3+1]) + __sinf(hv + rot[q*3+2]);
        }
        __syncthreads();
        for (int q = t; q < NQ_; q += 256) {
            float v;
            if (q == NQ_-1) v = 0.f;
            else {
                int qm = (q == 0) ? (NQ_-1) : (q-1);
                v = tb[q]*__sinf(ent[q]) + tb[qm]*__cosf(ent[q]);
            }
            ta[q] = v;
        }
        __syncthreads();
    }
    for (int q = t; q < NQ_; q += 256) h1f[(long)n*NQ_ + q] = ta[q];
}

// ---------------- bf16 MFMA GEMM (128x128, 2-phase, optional split-K) ----------------
template<int AMODE, int OMODE, bool RELU, int KSPLIT = 1>
__global__ __launch_bounds__(256) void k_bgemm(
    const short* __restrict__ A, const short* __restrict__ Bm,
    void* __restrict__ Cv, float* __restrict__ C2,
    const float* __restrict__ bias, float scale,
    int N, int K, int lda, int ldb, int ldc,
    long sA, long sB, long sC)
{
    __shared__ short lds[2][8192];
    const int t = threadIdx.x;
    const int lane = t & 63, wave = t >> 6;
    const int wm = wave >> 1, wn = wave & 1;
    const int l15 = lane & 15, l4 = lane >> 4;

    int bx = blockIdx.x, by = blockIdx.y;
    if (KSPLIT == 1 && gridDim.z == 1) {
        int lin = by * gridDim.x + bx;
        int nwg = gridDim.x * gridDim.y;
        int xcd = lin & 7, pos = lin >> 3;
        int q = nwg >> 3, r = nwg & 7;
        int lin2 = (xcd < r ? xcd*(q+1) : r*(q+1) + (xcd-r)*q) + pos;
        bx = lin2 % gridDim.x;
        by = lin2 / gridDim.x;
    }
    const int tile_m = bx * 128, tile_n = by * 128;
    const int kz = (KSPLIT > 1) ? blockIdx.z : 0;
    const int Keff = K / KSPLIT;
    const int kbase = kz * Keff;
    const long aoff = (KSPLIT > 1) ? 0 : (long)blockIdx.z * sA;
    const long boff = (KSPLIT > 1) ? 0 : (long)blockIdx.z * sB;
    const long coff = (KSPLIT > 1) ? 0 : (long)blockIdx.z * sC;

    const int cA0 = t, cA1 = t + 256;
    const int arow0 = tile_m + ((cA0 >> 6) << 4) + (cA0 & 15);
    const int arow1 = tile_m + ((cA1 >> 6) << 4) + (cA1 & 15);
    const int akb0 = ((cA0 >> 4) & 3) * 8;
    const int akb1 = ((cA1 >> 4) & 3) * 8;
    const int bcol0 = tile_n + (((cA0 >> 4) & 7) << 4) + (cA0 & 15);
    const int bcol1 = tile_n + (((cA1 >> 4) & 7) << 4) + (cA1 & 15);
    const int bkb0 = (cA0 >> 7) * 8;
    const int bkb1 = (cA1 >> 7) * 8;
    const short* bp0 = Bm + boff + (long)bcol0*ldb + bkb0 + kbase;
    const short* bp1 = Bm + boff + (long)bcol1*ldb + bkb1 + kbase;
    const short* ap0 = nullptr; const short* ap1 = nullptr;
    long abase0 = 0, abase1 = 0;
    if (AMODE == 0) {
        ap0 = A + aoff + (long)arow0*lda + akb0 + kbase;
        ap1 = A + aoff + (long)arow1*lda + akb1 + kbase;
    } else {
        abase0 = ((long)((arow0 >> 10)*H_) * S_ + (arow0 & (S_-1))) * 64;
        abase1 = ((long)((arow1 >> 10)*H_) * S_ + (arow1 & (S_-1))) * 64;
    }
    const int wb = wave * 1024;

    auto stage = [&](int buf, int k0) {
        char* lb = (char*)&lds[buf][0];
        const short *a0, *a1;
        if (AMODE == 0) { a0 = ap0 + k0; a1 = ap1 + k0; }
        else {
            int ka0 = kbase + k0 + akb0, ka1 = kbase + k0 + akb1;
            a0 = A + abase0 + (long)(ka0 >> 6)*(S_*64) + (ka0 & 63);
            a1 = A + abase1 + (long)(ka1 >> 6)*(S_*64) + (ka1 & 63);
        }
        __builtin_amdgcn_global_load_lds((as1vp)a0,          (as3vp)(lb + wb),          16, 0, 0);
        __builtin_amdgcn_global_load_lds((as1vp)a1,          (as3vp)(lb + 4096 + wb),   16, 0, 0);
        __builtin_amdgcn_global_load_lds((as1vp)(bp0 + k0),  (as3vp)(lb + 8192 + wb),   16, 0, 0);
        __builtin_amdgcn_global_load_lds((as1vp)(bp1 + k0),  (as3vp)(lb + 12288 + wb),  16, 0, 0);
    };

    f32x4 acc[4][4] = {};
    const int nk = Keff >> 5;
    stage(0, 0);
    __syncthreads();
    int cur = 0;
    for (int ks = 0; ks < nk; ks++) {
        if (ks + 1 < nk) stage(cur ^ 1, (ks + 1) << 5);
        short8 af[4], bfv[4];
        const short* lb = &lds[cur][0];
        #pragma unroll
        for (int m = 0; m < 4; m++)
            af[m] = *(const short8*)(lb + (wm*4 + m)*512 + l4*128 + l15*8);
        #pragma unroll
        for (int n = 0; n < 4; n++)
            bfv[n] = *(const short8*)(lb + 4096 + l4*1024 + (wn*4 + n)*128 + l15*8);
        #pragma unroll
        for (int m = 0; m < 4; m++)
            #pragma unroll
            for (int n = 0; n < 4; n++)
                acc[m][n] = __builtin_amdgcn_mfma_f32_16x16x32_bf16(af[m], bfv[n], acc[m][n], 0, 0, 0);
        __syncthreads();
        cur ^= 1;
    }

    #pragma unroll
    for (int m = 0; m < 4; m++) {
        #pragma unroll
        for (int n = 0; n < 4; n++) {
            int col = tile_n + wn*64 + n*16 + l15;
            if (col >= N) continue;
            float bv = (bias && (KSPLIT == 1 || kz == 0)) ? bias[col] : 0.f;
            #pragma unroll
            for (int r = 0; r < 4; r++) {
                int row = tile_m + wm*64 + m*16 + l4*4 + r;
                float v = acc[m][n][r] * scale + bv;
                if (RELU) v = fmaxf(v, 0.f);
                if (OMODE == 0) {
                    if (KSPLIT > 1)
                        atomicAdd(&((float*)Cv)[(long)row*ldc + col], v);
                    else
                        ((float*)Cv)[coff + (long)row*ldc + col] = v;
                } else if (OMODE == 1) {
                    ((short*)Cv)[coff + (long)row*ldc + col] = f2bf(v);
                } else if (OMODE == 2) {
                    C2[coff + (long)row*ldc + col] = v;
                    ((short*)Cv)[coff + (long)row*ldc + col] = f2bf(v);
                } else {   // OMODE 5: fused QKV routing
                    int seg = (col >= 1536) ? 2 : ((col >= 768) ? 1 : 0);
                    int c = col - seg*768;
                    int hh = c >> 6, dd = c & 63;
                    int b = row >> 10, s = row & (S_-1);
                    long hidx = (long)(b*H_ + hh);
                    short* base = (short*)Cv;
                    if (seg < 2) base[(long)seg*QKVS + (hidx*S_ + s)*64 + dd] = f2bf(v);
                    else         base[2L*QKVS + (hidx*64 + dd)*S_ + s] = f2bf(v);
                }
            }
        }
    }
}

// ---------------- 256x256 ring-2 BK=64 MFMA GEMM (vocab): 64 MFMA per barrier ----------------
// A [M,K] bf16 (M%256==0), B [N,K] bf16 (N%256==0), K%64==0.
// 512 threads = 8 waves. LDS: 2 regions x 64 KiB (A half0|A half1|B half0|B half1,
// each 16 KiB fragment-linear) = 128 KiB.
// Per phase (BK=64): vmcnt(0) -> barrier -> stage(next region) -> 2x{12 ds_read, 32 MFMA}.
// Rationale (R12 vs R8 A/B): MFMA-per-barrier is the lever (16->202us, 32->167us).
// At 64 MFMA/phase the MFMA work (~614 cyc at 2 waves/SIMD) exceeds L2 load latency
// (~250-300 cyc; B panel L2-resident via XCD swizzle) so the drain is mostly hidden,
// and the phase count halves (24 -> 12).
// Race check: stage(p+1) overwrites the region read in phase p-1; any wave past
// barrier(p) has completed those ds_reads (consumed by its pre-barrier MFMAs).
__global__ __launch_bounds__(512, 1) void k_vgemm(
    const short* __restrict__ A, const short* __restrict__ Bm,
    float* __restrict__ C, const float* __restrict__ bias,
    int N, int K, int lda, int ldb, int ldc)
{
    extern __shared__ short lds[];   // 65536 shorts = 128 KiB
    const int t = threadIdx.x;
    const int lane = t & 63, wave = t >> 6;
    const int wm = wave >> 2, wn = wave & 3;
    const int l15 = lane & 15, l4 = lane >> 4;
    int bx = blockIdx.x, by = blockIdx.y;
    {   // XCD-chunked bijective swizzle
        int lin = by * gridDim.x + bx;
        int nwg = gridDim.x * gridDim.y;
        int xcd = lin & 7, pos = lin >> 3;
        int q = nwg >> 3, r = nwg & 7;
        int lin2 = (xcd < r ? xcd*(q+1) : r*(q+1) + (xcd-r)*q) + pos;
        bx = lin2 % gridDim.x; by = lin2 / gridDim.x;
    }
    const int tile_m = bx * 256, tile_n = by * 256;

    // staging cells (per 16 KiB half): cell c -> row=(c>>6)*16+(c&15), koff=((c>>4)&3)*8
    const int c0 = wave*128 + lane;
    const int c1 = c0 + 64;
    const int ar0 = ((c0 >> 6) << 4) + (c0 & 15), ak0 = ((c0 >> 4) & 3) << 3;
    const int ar1 = ((c1 >> 6) << 4) + (c1 & 15), ak1 = ((c1 >> 4) & 3) << 3;
    const short* pa0 = A + (long)(tile_m + ar0)*lda + ak0;
    const short* pa1 = A + (long)(tile_m + ar1)*lda + ak1;
    const short* pb0 = Bm + (long)(tile_n + ar0)*ldb + ak0;
    const short* pb1 = Bm + (long)(tile_n + ar1)*ldb + ak1;
    char* lb = (char*)lds;
    const int wb0 = wave*2048, wb1 = wave*2048 + 1024;

    auto stage = [&](int reg, int p) {
        int k = p << 6;
        char* ab = lb + reg*65536;
        __builtin_amdgcn_global_load_lds((as1vp)(pa0 + k),      (as3vp)(ab + wb0),          16, 0, 0);
        __builtin_amdgcn_global_load_lds((as1vp)(pa1 + k),      (as3vp)(ab + wb1),          16, 0, 0);
        __builtin_amdgcn_global_load_lds((as1vp)(pa0 + k + 32), (as3vp)(ab + 16384 + wb0),  16, 0, 0);
        __builtin_amdgcn_global_load_lds((as1vp)(pa1 + k + 32), (as3vp)(ab + 16384 + wb1),  16, 0, 0);
        __builtin_amdgcn_global_load_lds((as1vp)(pb0 + k),      (as3vp)(ab + 32768 + wb0),  16, 0, 0);
        __builtin_amdgcn_global_load_lds((as1vp)(pb1 + k),      (as3vp)(ab + 32768 + wb1),  16, 0, 0);
        __builtin_amdgcn_global_load_lds((as1vp)(pb0 + k + 32), (as3vp)(ab + 49152 + wb0),  16, 0, 0);
        __builtin_amdgcn_global_load_lds((as1vp)(pb1 + k + 32), (as3vp)(ab + 49152 + wb1),  16, 0, 0);
    };

    f32x4 acc[8][4] = {};
    const int nph = K >> 6;   // 12
    stage(0, 0);
    const int ard = ((wm*8) << 10) + (l4 << 8) + l15*16;          // + fr<<10 (within A half)
    const int brd = 32768 + ((wn*4) << 10) + (l4 << 8) + l15*16;  // + fc<<10 (within B half)

    for (int p = 0; p < nph; p++) {
        asm volatile("s_waitcnt vmcnt(0)" ::: "memory");
        __builtin_amdgcn_s_barrier();
        if (p + 1 < nph) stage((p + 1) & 1, p + 1);
        const char* rb = lb + (p & 1)*65536;
        #pragma unroll
        for (int h = 0; h < 2; h++) {
            short8 a[8], b[4];
            #pragma unroll
            for (int fr = 0; fr < 8; fr++)
                a[fr] = *(const short8*)(rb + h*16384 + ard + (fr << 10));
            #pragma unroll
            for (int fc = 0; fc < 4; fc++)
                b[fc] = *(const short8*)(rb + h*16384 + brd + (fc << 10));
            __builtin_amdgcn_s_setprio(1);
            #pragma unroll
            for (int fr = 0; fr < 8; fr++)
                #pragma unroll
                for (int fc = 0; fc < 4; fc++)
                    acc[fr][fc] = __builtin_amdgcn_mfma_f32_16x16x32_bf16(a[fr], b[fc], acc[fr][fc], 0, 0, 0);
            __builtin_amdgcn_s_setprio(0);
        }
    }

    #pragma unroll
    for (int fr = 0; fr < 8; fr++) {
        #pragma unroll
        for (int fc = 0; fc < 4; fc++) {
            int col = tile_n + wn*64 + fc*16 + l15;
            float bv = bias ? bias[col] : 0.f;
            #pragma unroll
            for (int rr = 0; rr < 4; rr++) {
                int row = tile_m + wm*128 + fr*16 + l4*4 + rr;
                C[(long)row*ldc + col] = acc[fr][fc][rr] + bv;
            }
        }
    }
}

// ---------------- flash attention: QK^T/8 + mask-bug + online softmax + PV ----------------
__global__ __launch_bounds__(256) void k_fattn(
    const short* __restrict__ Q, const short* __restrict__ K,
    const short* __restrict__ Vt, const int* __restrict__ mask,
    short* __restrict__ ctx)
{
    __shared__ short plds[4096];   // 4 waves x [16 q][64 kv]
    const int t = threadIdx.x;
    const int lane = t & 63, wave = t >> 6;
    const int l15 = lane & 15, l4 = lane >> 4;
    const int qt = blockIdx.x, z = blockIdx.y;
    const int b = z / H_;
    const long zb = (long)z * S_ * 64;

    const int q = qt*64 + wave*16 + l15;
    short8 aq0 = *(const short8*)(Q + zb + (long)q*64 + l4*8);
    short8 aq1 = *(const short8*)(Q + zb + (long)q*64 + l4*8 + 32);

    float m[4] = {-1e30f, -1e30f, -1e30f, -1e30f};
    float l[4] = {0.f, 0.f, 0.f, 0.f};
    f32x4 O[4] = {};
    short* pw = plds + wave*1024;

    for (int kt = 0; kt < 16; kt++) {
        const int kvb = kt*64;
        f32x4 s[4] = {};
        #pragma unroll
        for (int ct = 0; ct < 4; ct++) {
            const short* kp = K + zb + (long)(kvb + ct*16 + l15)*64 + l4*8;
            short8 b0 = *(const short8*)(kp);
            short8 b1 = *(const short8*)(kp + 32);
            s[ct] = __builtin_amdgcn_mfma_f32_16x16x32_bf16(aq0, b0, s[ct], 0, 0, 0);
            s[ct] = __builtin_amdgcn_mfma_f32_16x16x32_bf16(aq1, b1, s[ct], 0, 0, 0);
        }
        float p[4][4];
        float rmax[4] = {-1e30f, -1e30f, -1e30f, -1e30f};
        #pragma unroll
        for (int ct = 0; ct < 4; ct++) {
            int mv = mask[b*S_ + kvb + ct*16 + l15];
            #pragma unroll
            for (int r = 0; r < 4; r++) {
                float v = (mv == 1) ? -1e9f : s[ct][r]*0.125f;
                p[ct][r] = v;
                rmax[r] = fmaxf(rmax[r], v);
            }
        }
        #pragma unroll
        for (int r = 0; r < 4; r++) {
            float v = rmax[r];
            v = fmaxf(v, __shfl_xor(v, 1));
            v = fmaxf(v, __shfl_xor(v, 2));
            v = fmaxf(v, __shfl_xor(v, 4));
            v = fmaxf(v, __shfl_xor(v, 8));
            float mn = fmaxf(m[r], v);
            float corr = __expf(m[r] - mn);
            float srow = 0.f;
            #pragma unroll
            for (int ct = 0; ct < 4; ct++) {
                float e = __expf(p[ct][r] - mn);
                p[ct][r] = e;
                srow += e;
            }
            srow += __shfl_xor(srow, 1);
            srow += __shfl_xor(srow, 2);
            srow += __shfl_xor(srow, 4);
            srow += __shfl_xor(srow, 8);
            l[r] = l[r]*corr + srow;
            m[r] = mn;
            #pragma unroll
            for (int c2 = 0; c2 < 4; c2++) O[c2][r] *= corr;
        }
        #pragma unroll
        for (int ct = 0; ct < 4; ct++)
            #pragma unroll
            for (int r = 0; r < 4; r++)
                pw[(l4*4 + r)*64 + ct*16 + l15] = f2bf(p[ct][r]);
        asm volatile("s_waitcnt lgkmcnt(0)" ::: "memory");
        __builtin_amdgcn_sched_barrier(0);
        short8 pa0 = *(const short8*)(pw + l15*64 + l4*8);
        short8 pa1 = *(const short8*)(pw + l15*64 + l4*8 + 32);
        #pragma unroll
        for (int c2 = 0; c2 < 4; c2++) {
            const short* vp = Vt + zb + (long)(c2*16 + l15)*S_ + kvb + l4*8;
            short8 v0 = *(const short8*)(vp);
            short8 v1 = *(const short8*)(vp + 32);
            O[c2] = __builtin_amdgcn_mfma_f32_16x16x32_bf16(pa0, v0, O[c2], 0, 0, 0);
            O[c2] = __builtin_amdgcn_mfma_f32_16x16x32_bf16(pa1, v1, O[c2], 0, 0, 0);
        }
    }
    #pragma unroll
    for (int r = 0; r < 4; r++) {
        float inv = 1.f / l[r];
        int qo = qt*64 + wave*16 + l4*4 + r;
        #pragma unroll
        for (int c2 = 0; c2 < 4; c2++)
            ctx[zb + (long)qo*64 + c2*16 + l15] = f2bf(O[c2][r] * inv);
    }
}

// ---------------- mega prep: ALL weight transposes/converts/biases in one launch ----------------
struct WPArgs {
    const float *ow, *wq, *wk, *wv, *wo, *g1, *g2, *f1, *f2, *adj;
    const float *w1, *w3, *w5, *wp, *b1, *b3, *b5, *bq, *bk, *bv;
    short *owt, *wqkvt, *gw1t, *gw2t, *fw1t, *fw2t, *adjb, *wincat, *wincp;
    float *binc, *bqkv;
};
__global__ __launch_bounds__(256) void k_wprep(WPArgs a) {
    __shared__ float tile[32][33];
    int blk = blockIdx.x, t = threadIdx.x;
    const float* src; short* dst;
    int R, C, bx, by;
    if (blk < 24000)      { src = a.ow; dst = a.owt; R = 768; C = 32000; bx = blk % 1000; by = blk / 1000; }
    else if (blk < 26304) { int r = blk - 24000; int z = r / 576; r %= 576;
        src = (z == 0) ? a.wq : (z == 1) ? a.wk : (z == 2) ? a.wv : a.wo;
        dst = a.wqkvt + (long)z*589824; R = 768; C = 768; bx = r % 24; by = r / 24; }
    else if (blk < 26592) { int r = blk - 26304; src = a.g1; dst = a.gw1t; R = 768; C = 384;  bx = r % 12; by = r / 12; }
    else if (blk < 26880) { int r = blk - 26592; src = a.g2; dst = a.gw2t; R = 384; C = 768;  bx = r % 24; by = r / 24; }
    else if (blk < 29184) { int r = blk - 26880; src = a.f1; dst = a.fw1t; R = 768; C = 3072; bx = r % 96; by = r / 96; }
    else if (blk < 31488) { int r = blk - 29184; src = a.f2; dst = a.fw2t; R = 3072; C = 768; bx = r % 24; by = r / 24; }
    else if (blk < 33536) {
        long i = ((long)(blk - 31488)*256 + t)*4;
        f32x4 v = *(const f32x4*)(a.adj + i);
        a.adjb[i+0] = f2bf(v.x); a.adjb[i+1] = f2bf(v.y);
        a.adjb[i+2] = f2bf(v.z); a.adjb[i+3] = f2bf(v.w);
        return;
    } else {
        int r = blk - 33536;
        const float* s2; short* d2; long base;
        if (r < 48)       { s2 = a.w1; d2 = a.wincat;          base = (long)r*1024; }
        else if (r < 120) { s2 = a.w3; d2 = a.wincat + 49152;  base = (long)(r-48)*1024; }
        else if (r < 132) { s2 = a.w5; d2 = a.wincat + 122880; base = (long)(r-120)*1024; }
        else if (r < 156) { s2 = a.wp; d2 = a.wincp;           base = (long)(r-132)*1024; }
        else {
            if (t < 176) a.binc[t] = (t < 64) ? a.b1[t] : (t < 160 ? a.b3[t-64] : a.b5[t-160]);
            for (int i = t; i < 2304; i += 256)
                a.bqkv[i] = (i < 768) ? a.bq[i] : (i < 1536 ? a.bk[i-768] : a.bv[i-1536]);
            return;
        }
        long i = base + (long)t*4;
        f32x4 v = *(const f32x4*)(s2 + i);
        d2[i+0] = f2bf(v.x); d2[i+1] = f2bf(v.y); d2[i+2] = f2bf(v.z); d2[i+3] = f2bf(v.w);
        return;
    }
    int bc = bx*32, br = by*32;
    int tx = t & 31, ty = t >> 5;
    #pragma unroll
    for (int i = 0; i < 32; i += 8)
        tile[ty + i][tx] = src[(long)(br + ty + i)*C + bc + tx];
    __syncthreads();
    #pragma unroll
    for (int i = 0; i < 32; i += 8)
        dst[(long)(bc + ty + i)*R + br + tx] = f2bf(tile[tx][ty + i]);
}

// ---------------- f32 [R,C] -> bf16 [C,R] transpose-convert (batched, opt. relu) ----------------
template<bool RELU>
__global__ void k_t2b(const float* __restrict__ in, short* __restrict__ out,
                      int R, int C, long sIn, long sOut) {
    __shared__ float tile[32][33];
    int bc = blockIdx.x * 32, br = blockIdx.y * 32;
    const float* ip = in + (long)blockIdx.z * sIn;
    short* op = out + (long)blockIdx.z * sOut;
    int tx = threadIdx.x & 31, ty = threadIdx.x >> 5;
    #pragma unroll
    for (int i = 0; i < 32; i += 8)
        tile[ty + i][tx] = ip[(long)(br + ty + i)*C + bc + tx];
    __syncthreads();
    #pragma unroll
    for (int i = 0; i < 32; i += 8) {
        float v = tile[tx][ty + i];
        if (RELU) v = fmaxf(v, 0.f);
        op[(long)(bc + ty + i)*R + br + tx] = f2bf(v);
    }
}

// ---------------- residual add + LayerNorm (f32 out optional + bf16 out) ----------------
__global__ void k_addln(const float* __restrict__ a, const float* __restrict__ bvec,
                        const float* __restrict__ g, const float* __restrict__ be,
                        float* __restrict__ outf, short* __restrict__ outb) {
    __shared__ float row[D_];
    __shared__ float red[256];
    int n = blockIdx.x, t = threadIdx.x;
    float lsum = 0.f;
    for (int d = t; d < D_; d += 256) {
        float v = a[(long)n*D_ + d] + bvec[(long)n*D_ + d];
        row[d] = v; lsum += v;
    }
    red[t] = lsum; __syncthreads();
    for (int off = 128; off > 0; off >>= 1) {
        if (t < off) red[t] += red[t+off];
        __syncthreads();
    }
    float mean = red[0] / D_; __syncthreads();
    float lvar = 0.f;
    for (int d = t; d < D_; d += 256) { float v = row[d]-mean; lvar += v*v; }
    red[t] = lvar; __syncthreads();
    for (int off = 128; off > 0; off >>= 1) {
        if (t < off) red[t] += red[t+off];
        __syncthreads();
    }
    float rstd = rsqrtf(red[0]/D_ + 1e-5f);
    for (int d = t; d < D_; d += 256) {
        float v = (row[d]-mean)*rstd*g[d] + be[d];
        if (outf) outf[(long)n*D_ + d] = v;
        outb[(long)n*D_ + d] = f2bf(v);
    }
}

// ---------------- mean-pool over sequence (parallel partials + atomics) ----------------
__global__ __launch_bounds__(256) void k_pool(const short* __restrict__ h,
                                              float* __restrict__ pooled) {
    int blk = blockIdx.x;
    int b = blk >> 4, ch = blk & 15;
    int t = threadIdx.x;
    float s0 = 0.f, s1 = 0.f, s2 = 0.f;
    for (int ss = ch*64; ss < ch*64 + 64; ss++) {
        const short* row = h + (long)(b*S_ + ss)*D_;
        s0 += b2fs(row[t]);
        s1 += b2fs(row[t + 256]);
        s2 += b2fs(row[t + 512]);
    }
    atomicAdd(&pooled[b*D_ + t],       s0 * (1.f/S_));
    atomicAdd(&pooled[b*D_ + t + 256], s1 * (1.f/S_));
    atomicAdd(&pooled[b*D_ + t + 512], s2 * (1.f/S_));
}

// ---------------- task head (parallel reduce; block per batch) ----------------
__global__ __launch_bounds__(256) void k_task(const float* __restrict__ pooled,
                                              const float* __restrict__ tw,
                                              const float* __restrict__ tb,
                                              float* __restrict__ out) {
    __shared__ float red[256][3];
    int b = blockIdx.x, t = threadIdx.x;
    float a0 = 0.f, a1 = 0.f, a2 = 0.f;
    for (int d = t; d < D_; d += 256) {
        float p = pooled[b*D_ + d];
        a0 += p*tw[d*3+0]; a1 += p*tw[d*3+1]; a2 += p*tw[d*3+2];
    }
    red[t][0] = a0; red[t][1] = a1; red[t][2] = a2;
    __syncthreads();
    for (int off = 128; off > 0; off >>= 1) {
        if (t < off) {
            red[t][0] += red[t+off][0];
            red[t][1] += red[t+off][1];
            red[t][2] += red[t+off][2];
        }
        __syncthreads();
    }
    if (t < 3) out[(long)NTOK*V_ + b*3 + t] = red[0][t] + tb[t];
}

extern "C" void kernel_launch(void* const* d_in, const int* in_sizes, int n_in,
                              void* d_out, int out_size, void* d_ws, size_t ws_size,
                              hipStream_t stream) {
    const int*   x      = (const int*)d_in[0];
    const int*   amask  = (const int*)d_in[1];
    const float* adj    = (const float*)d_in[2];
    const float* emb    = (const float*)d_in[3];
    const float* inc1_w = (const float*)d_in[4];  const float* inc1_b = (const float*)d_in[5];
    const float* inc3a_w= (const float*)d_in[6];  const float* inc3a_b= (const float*)d_in[7];
    const float* inc3b_w= (const float*)d_in[8];  const float* inc3b_b= (const float*)d_in[9];
    const float* inc5a_w= (const float*)d_in[10]; const float* inc5a_b= (const float*)d_in[11];
    const float* inc5b_w= (const float*)d_in[12]; const float* inc5b_b= (const float*)d_in[13];
    const float* incp_w = (const float*)d_in[14]; const float* incp_b = (const float*)d_in[15];
    const float* q_rot  = (const float*)d_in[16]; const float* q_ent  = (const float*)d_in[17];
    const float* gnn_w1 = (const float*)d_in[18]; const float* gnn_b1 = (const float*)d_in[19];
    const float* gnn_w2 = (const float*)d_in[20]; const float* gnn_b2 = (const float*)d_in[21];
    const float* wq = (const float*)d_in[22]; const float* bq = (const float*)d_in[23];
    const float* wk = (const float*)d_in[24]; const float* bk = (const float*)d_in[25];
    const float* wv = (const float*)d_in[26]; const float* bv = (const float*)d_in[27];
    const float* wo = (const float*)d_in[28]; const float* bo = (const float*)d_in[29];
    const float* ff_w1 = (const float*)d_in[30]; const float* ff_b1 = (const float*)d_in[31];
    const float* ff_w2 = (const float*)d_in[32]; const float* ff_b2 = (const float*)d_in[33];
    const float* ln1_g = (const float*)d_in[34]; const float* ln1_b = (const float*)d_in[35];
    const float* ln2_g = (const float*)d_in[36]; const float* ln2_b = (const float*)d_in[37];
    const float* out_w = (const float*)d_in[38]; const float* out_b = (const float*)d_in[39];
    const float* task_w= (const float*)d_in[40]; const float* task_b= (const float*)d_in[41];

    // ---- d_out arena (f32 slot offsets; non-overlapping; dead before vocab GEMM) ----
    float* F = (float*)d_out;
    short* wqkvt = (short*)(F + 0L);
    short* gw1t  = (short*)(F + 1179648L);
    short* gw2t  = (short*)(F + 1327104L);
    short* fw1t  = (short*)(F + 1474560L);
    short* fw2t  = (short*)(F + 2654208L);
    short* wincat= (short*)(F + 3833856L);
    short* wincp = (short*)(F + 3950592L);
    float* binc  = F + 4012032L;
    float* bqkv  = F + 4012288L;
    short* adjb  = (short*)(F + 4014592L);
    short* h0b   = (short*)(F + 5063168L);
    short* mpb   = (short*)(F + 5849600L);
    float* CO    = F + 6636032L;
    float* h1f   = F + 6996480L;
    short* h1t   = (short*)(F + 8569344L);
    short* t1b   = (short*)(F + 9355776L);
    float* gbf   = F + 10142208L;
    short* gt    = (short*)(F + 10928640L);
    short* t2bv  = (short*)(F + 11321856L);
    float* h2f   = F + 11715072L;
    short* h2b   = (short*)(F + 13287936L);
    short* Qh    = (short*)(F + 14074368L);
    short* Kh    = (short*)(F + 14860800L);
    short* Vt    = (short*)(F + 15647232L);
    short* ctxh  = (short*)(F + 16499200L);
    float* ao    = F + 17285632L;
    float* hlnf  = F + 18858496L;
    short* hlnb  = (short*)(F + 20431360L);
    short* ff1b  = (short*)(F + 21217792L);
    float* ao2   = F + 24363520L;

    // ---- d_ws ----
    char* W = (char*)d_ws;
    short* hfb    = (short*)(W + 0);
    float* pooled = (float*)(W + 3145728);
    short* owt    = (short*)(W + 3151872);

    auto gb = [](int M, int N, int Z) { return dim3((unsigned)(M/128), (unsigned)((N+127)/128), (unsigned)Z); };

    hipFuncSetAttribute((const void*)k_vgemm, hipFuncAttributeMaxDynamicSharedMemorySize, 131072);

    // 0a. zero split-K accumulators + atomic targets
    hipMemsetAsync(gbf, 0, (size_t)NTOK*384*4, stream);
    hipMemsetAsync(ao,  0, (size_t)NTOK*D_*4, stream);
    hipMemsetAsync(ao2, 0, (size_t)NTOK*D_*4, stream);
    hipMemsetAsync(CO,  0, (size_t)NTOK*176*4, stream);
    hipMemsetAsync(h1f, 0, (size_t)NTOK*NQ_*4, stream);
    hipMemsetAsync(pooled, 0, (size_t)B_*D_*4, stream);

    // 0b. ALL one-time converts/transposes/bias concats in ONE launch
    {
        WPArgs wa;
        wa.ow = out_w; wa.wq = wq; wa.wk = wk; wa.wv = wv; wa.wo = wo;
        wa.g1 = gnn_w1; wa.g2 = gnn_w2; wa.f1 = ff_w1; wa.f2 = ff_w2; wa.adj = adj;
        wa.w1 = inc1_w; wa.w3 = inc3a_w; wa.w5 = inc5a_w; wa.wp = incp_w;
        wa.b1 = inc1_b; wa.b3 = inc3a_b; wa.b5 = inc5a_b;
        wa.bq = bq; wa.bk = bk; wa.bv = bv;
        wa.owt = owt; wa.wqkvt = wqkvt; wa.gw1t = gw1t; wa.gw2t = gw2t;
        wa.fw1t = fw1t; wa.fw2t = fw2t; wa.adjb = adjb;
        wa.wincat = wincat; wa.wincp = wincp; wa.binc = binc; wa.bqkv = bqkv;
        k_wprep<<<dim3(33693), 256, 0, stream>>>(wa);
    }

    // 1. embedding + maxpool fused (bf16)
    k_embed2<<<dim3(NTOK), dim3(256), 0, stream>>>(x, emb, h0b, mpb);

    // 2. inception 1x1 GEMMs, split-K for occupancy
    k_bgemm<0,0,false,4><<<gb(NTOK, 176, 4), 256, 0, stream>>>(
        h0b, wincat, CO, nullptr, binc, 1.f, 176, D_, D_, D_, 176, 0, 0, 0);
    k_bgemm<0,0,false,8><<<gb(NTOK, 32, 8), 256, 0, stream>>>(
        mpb, wincp, h1f + 224, nullptr, incp_b, 1.f, 32, D_, D_, D_, NQ_, 0, 0, 0);

    // 3. fused conv3/conv5/copy/quantum x2
    k_mix<<<dim3(NTOK), dim3(256), 0, stream>>>(
        CO, inc3b_w, inc3b_b, inc5b_w, inc5b_b, q_rot, q_ent, h1f);

    // 4. GNN
    k_t2b<false><<<dim3(24,32,2), 256, 0, stream>>>(h1f, h1t, S_, NQ_, (long)S_*NQ_, (long)S_*NQ_);
    k_bgemm<0,1,false><<<gb(S_, NQ_, B_), 256, 0, stream>>>(
        adjb, h1t, t1b, nullptr, nullptr, 1.f, NQ_, S_, S_, S_, NQ_,
        (long)S_*S_, (long)NQ_*S_, (long)S_*NQ_);
    k_bgemm<0,0,false,4><<<gb(NTOK, 384, 4), 256, 0, stream>>>(
        t1b, gw1t, gbf, nullptr, gnn_b1, 1.f, 384, D_, D_, D_, 384, 0, 0, 0);
    k_t2b<true><<<dim3(12,32,2), 256, 0, stream>>>(gbf, gt, S_, 384, (long)S_*384, (long)S_*384);
    k_bgemm<0,1,false><<<gb(S_, 384, B_), 256, 0, stream>>>(
        adjb, gt, t2bv, nullptr, nullptr, 1.f, 384, S_, S_, S_, 384,
        (long)S_*S_, (long)384*S_, (long)S_*384);
    k_bgemm<0,2,false><<<gb(NTOK, D_, 1), 256, 0, stream>>>(
        t2bv, gw2t, h2b, h2f, gnn_b2, 1.f, D_, 384, 384, 384, D_, 0, 0, 0);

    // 5. attention: fused QKV -> flash attention -> WO -> add+LN
    k_bgemm<0,5,false><<<gb(NTOK, 3*D_, 1), 256, 0, stream>>>(
        h2b, wqkvt, Qh, nullptr, bqkv, 1.f, 3*D_, D_, D_, D_, 0, 0, 0, 0);
    k_fattn<<<dim3(S_/64, B_*H_), 256, 0, stream>>>(Qh, Kh, Vt, amask, ctxh);
    k_bgemm<1,0,false,2><<<gb(NTOK, D_, 2), 256, 0, stream>>>(
        ctxh, wqkvt + 3L*589824, ao, nullptr, bo, 1.f, D_, D_, D_, D_, D_, 0, 0, 0);
    k_addln<<<dim3(NTOK), dim3(256), 0, stream>>>(h2f, ao, ln1_g, ln1_b, hlnf, hlnb);

    // 6. FFN
    k_bgemm<0,1,true><<<gb(NTOK, 4*D_, 1), 256, 0, stream>>>(
        hlnb, fw1t, ff1b, nullptr, ff_b1, 1.f, 4*D_, D_, D_, D_, 4*D_, 0, 0, 0);
    k_bgemm<0,0,false,4><<<gb(NTOK, D_, 4), 256, 0, stream>>>(
        ff1b, fw2t, ao2, nullptr, ff_b2, 1.f, D_, 4*D_, 4*D_, 4*D_, D_, 0, 0, 0);
    k_addln<<<dim3(NTOK), dim3(256), 0, stream>>>(hlnf, ao2, ln2_g, ln2_b, nullptr, hfb);

    // 7. heads: parallel pool, vocab GEMM (256^2 ring-2 BK=64), parallel task
    k_pool<<<dim3(B_*16), dim3(256), 0, stream>>>(hfb, pooled);
    k_vgemm<<<dim3(NTOK/256, V_/256, 1), dim3(512), 131072, stream>>>(
        hfb, owt, (float*)d_out, out_b, V_, D_, D_, D_, V_);
    k_task<<<dim3(B_), dim3(256), 0, stream>>>(pooled, task_w, task_b, (float*)d_out);
}

// Round 18
// 636.124 us; speedup vs baseline: 1.0220x; 1.0220x over previous
//
#include <hip/hip_runtime.h>
#include <hip/hip_bf16.h>

#define B_ 2
#define S_ 1024
#define D_ 768
#define H_ 12
#define HD_ 64
#define V_ 32000
#define NQ_ 768
#define NTOK (B_*S_)
#define QKVS 1572864L   // shorts per Q/K/V segment [B,H,S,64]

typedef __attribute__((ext_vector_type(8))) short short8;
typedef __attribute__((ext_vector_type(4))) short s16x4;
typedef __attribute__((ext_vector_type(4))) float f32x4;
typedef __attribute__((ext_vector_type(4))) int i32x4;

typedef const __attribute__((address_space(1))) void* as1vp;
typedef __attribute__((address_space(3))) void* as3vp;

__device__ __forceinline__ short f2bf(float f) {
    union { float f; unsigned u; } v; v.f = f;
    unsigned r = (v.u + 0x7FFFu + ((v.u >> 16) & 1u)) >> 16;
    return (short)r;
}
__device__ __forceinline__ float b2fs(short s) {
    union { unsigned u; float f; } v; v.u = ((unsigned)(unsigned short)s) << 16;
    return v.f;
}

// ---------------- embedding + maxpool3 fused ----------------
__global__ void k_embed2(const int* __restrict__ x, const float* __restrict__ emb,
                         short* __restrict__ h0b, short* __restrict__ mpb) {
    int n = blockIdx.x; int s = n & (S_-1);
    int r0 = x[n];
    int rm = (s > 0)      ? x[n-1] : -1;
    int rp = (s < S_-1)   ? x[n+1] : -1;
    for (int d = threadIdx.x; d < D_; d += blockDim.x) {
        float e = emb[(long)r0*D_ + d];
        float m = e;
        if (rm >= 0) m = fmaxf(m, emb[(long)rm*D_ + d]);
        if (rp >= 0) m = fmaxf(m, emb[(long)rp*D_ + d]);
        h0b[(long)n*D_ + d] = f2bf(e);
        mpb[(long)n*D_ + d] = f2bf(m);
    }
}

// ---------------- fused conv3+conv5+copy+incp-merge+quantum x2 ----------------
__global__ __launch_bounds__(256) void k_mix(
    const float* __restrict__ CO, const float* __restrict__ c3w,
    const float* __restrict__ c3b, const float* __restrict__ c5w,
    const float* __restrict__ c5b, const float* __restrict__ q_rot,
    const float* __restrict__ q_ent, float* __restrict__ h1f)
{
    __shared__ float co[5][176];
    __shared__ float ta[NQ_];
    __shared__ float tb[NQ_];
    int n = blockIdx.x; int s = n & (S_-1);
    int t = threadIdx.x;
    for (int idx = t; idx < 5*176; idx += 256) {
        int dr = idx / 176 - 2, c = idx % 176;
        int ss = s + dr;
        co[idx/176][c] = (ss >= 0 && ss < S_) ? CO[(long)(n + dr)*176 + c] : 0.f;
    }
    for (int d = 256 + t; d < NQ_; d += 256) ta[d] = 0.f;
    __syncthreads();
    if (t < 64) {
        ta[t] = co[2][t];
    } else if (t < 192) {
        int o = t - 64;
        float acc = c3b[o];
        #pragma unroll
        for (int k = 0; k < 3; k++)
            for (int i = 0; i < 96; i++)
                acc += co[1+k][64+i] * c3w[(o*96+i)*3 + k];
        ta[t] = acc;
    } else if (t < 224) {
        int o = t - 192;
        float acc = c5b[o];
        #pragma unroll
        for (int k = 0; k < 5; k++)
            for (int i = 0; i < 16; i++)
                acc += co[k][160+i] * c5w[(o*16+i)*5 + k];
        ta[t] = acc;
    } else {
        ta[t] = h1f[(long)n*NQ_ + t];
    }
    __syncthreads();
    #pragma unroll
    for (int layer = 0; layer < 2; layer++) {
        const float* rot = q_rot + (long)layer*NQ_*3;
        const float* ent = q_ent + (long)layer*(NQ_-1);
        for (int q = t; q < NQ_; q += 256) {
            float hv = ta[q];
            tb[q] = __sinf(hv + rot[q*3]) + __sinf(hv + rot[q*3+1]) + __sinf(hv + rot[q*3+2]);
        }
        __syncthreads();
        for (int q = t; q < NQ_; q += 256) {
            float v;
            if (q == NQ_-1) v = 0.f;
            else {
                int qm = (q == 0) ? (NQ_-1) : (q-1);
                v = tb[q]*__sinf(ent[q]) + tb[qm]*__cosf(ent[q]);
            }
            ta[q] = v;
        }
        __syncthreads();
    }
    for (int q = t; q < NQ_; q += 256) h1f[(long)n*NQ_ + q] = ta[q];
}

// ---------------- bf16 MFMA GEMM (128x128, 2-phase, optional split-K) ----------------
template<int AMODE, int OMODE, bool RELU, int KSPLIT = 1>
__global__ __launch_bounds__(256) void k_bgemm(
    const short* __restrict__ A, const short* __restrict__ Bm,
    void* __restrict__ Cv, float* __restrict__ C2,
    const float* __restrict__ bias, float scale,
    int N, int K, int lda, int ldb, int ldc,
    long sA, long sB, long sC)
{
    __shared__ short lds[2][8192];
    const int t = threadIdx.x;
    const int lane = t & 63, wave = t >> 6;
    const int wm = wave >> 1, wn = wave & 1;
    const int l15 = lane & 15, l4 = lane >> 4;

    int bx = blockIdx.x, by = blockIdx.y;
    if (KSPLIT == 1 && gridDim.z == 1) {
        int lin = by * gridDim.x + bx;
        int nwg = gridDim.x * gridDim.y;
        int xcd = lin & 7, pos = lin >> 3;
        int q = nwg >> 3, r = nwg & 7;
        int lin2 = (xcd < r ? xcd*(q+1) : r*(q+1) + (xcd-r)*q) + pos;
        bx = lin2 % gridDim.x;
        by = lin2 / gridDim.x;
    }
    const int tile_m = bx * 128, tile_n = by * 128;
    const int kz = (KSPLIT > 1) ? blockIdx.z : 0;
    const int Keff = K / KSPLIT;
    const int kbase = kz * Keff;
    const long aoff = (KSPLIT > 1) ? 0 : (long)blockIdx.z * sA;
    const long boff = (KSPLIT > 1) ? 0 : (long)blockIdx.z * sB;
    const long coff = (KSPLIT > 1) ? 0 : (long)blockIdx.z * sC;

    const int cA0 = t, cA1 = t + 256;
    const int arow0 = tile_m + ((cA0 >> 6) << 4) + (cA0 & 15);
    const int arow1 = tile_m + ((cA1 >> 6) << 4) + (cA1 & 15);
    const int akb0 = ((cA0 >> 4) & 3) * 8;
    const int akb1 = ((cA1 >> 4) & 3) * 8;
    const int bcol0 = tile_n + (((cA0 >> 4) & 7) << 4) + (cA0 & 15);
    const int bcol1 = tile_n + (((cA1 >> 4) & 7) << 4) + (cA1 & 15);
    const int bkb0 = (cA0 >> 7) * 8;
    const int bkb1 = (cA1 >> 7) * 8;
    const short* bp0 = Bm + boff + (long)bcol0*ldb + bkb0 + kbase;
    const short* bp1 = Bm + boff + (long)bcol1*ldb + bkb1 + kbase;
    const short* ap0 = nullptr; const short* ap1 = nullptr;
    long abase0 = 0, abase1 = 0;
    if (AMODE == 0) {
        ap0 = A + aoff + (long)arow0*lda + akb0 + kbase;
        ap1 = A + aoff + (long)arow1*lda + akb1 + kbase;
    } else {
        abase0 = ((long)((arow0 >> 10)*H_) * S_ + (arow0 & (S_-1))) * 64;
        abase1 = ((long)((arow1 >> 10)*H_) * S_ + (arow1 & (S_-1))) * 64;
    }
    const int wb = wave * 1024;

    auto stage = [&](int buf, int k0) {
        char* lb = (char*)&lds[buf][0];
        const short *a0, *a1;
        if (AMODE == 0) { a0 = ap0 + k0; a1 = ap1 + k0; }
        else {
            int ka0 = kbase + k0 + akb0, ka1 = kbase + k0 + akb1;
            a0 = A + abase0 + (long)(ka0 >> 6)*(S_*64) + (ka0 & 63);
            a1 = A + abase1 + (long)(ka1 >> 6)*(S_*64) + (ka1 & 63);
        }
        __builtin_amdgcn_global_load_lds((as1vp)a0,          (as3vp)(lb + wb),          16, 0, 0);
        __builtin_amdgcn_global_load_lds((as1vp)a1,          (as3vp)(lb + 4096 + wb),   16, 0, 0);
        __builtin_amdgcn_global_load_lds((as1vp)(bp0 + k0),  (as3vp)(lb + 8192 + wb),   16, 0, 0);
        __builtin_amdgcn_global_load_lds((as1vp)(bp1 + k0),  (as3vp)(lb + 12288 + wb),  16, 0, 0);
    };

    f32x4 acc[4][4] = {};
    const int nk = Keff >> 5;
    stage(0, 0);
    __syncthreads();
    int cur = 0;
    for (int ks = 0; ks < nk; ks++) {
        if (ks + 1 < nk) stage(cur ^ 1, (ks + 1) << 5);
        short8 af[4], bfv[4];
        const short* lb = &lds[cur][0];
        #pragma unroll
        for (int m = 0; m < 4; m++)
            af[m] = *(const short8*)(lb + (wm*4 + m)*512 + l4*128 + l15*8);
        #pragma unroll
        for (int n = 0; n < 4; n++)
            bfv[n] = *(const short8*)(lb + 4096 + l4*1024 + (wn*4 + n)*128 + l15*8);
        #pragma unroll
        for (int m = 0; m < 4; m++)
            #pragma unroll
            for (int n = 0; n < 4; n++)
                acc[m][n] = __builtin_amdgcn_mfma_f32_16x16x32_bf16(af[m], bfv[n], acc[m][n], 0, 0, 0);
        __syncthreads();
        cur ^= 1;
    }

    #pragma unroll
    for (int m = 0; m < 4; m++) {
        #pragma unroll
        for (int n = 0; n < 4; n++) {
            int col = tile_n + wn*64 + n*16 + l15;
            if (col >= N) continue;
            float bv = (bias && (KSPLIT == 1 || kz == 0)) ? bias[col] : 0.f;
            #pragma unroll
            for (int r = 0; r < 4; r++) {
                int row = tile_m + wm*64 + m*16 + l4*4 + r;
                float v = acc[m][n][r] * scale + bv;
                if (RELU) v = fmaxf(v, 0.f);
                if (OMODE == 0) {
                    if (KSPLIT > 1)
                        atomicAdd(&((float*)Cv)[(long)row*ldc + col], v);
                    else
                        ((float*)Cv)[coff + (long)row*ldc + col] = v;
                } else if (OMODE == 1) {
                    ((short*)Cv)[coff + (long)row*ldc + col] = f2bf(v);
                } else if (OMODE == 2) {
                    C2[coff + (long)row*ldc + col] = v;
                    ((short*)Cv)[coff + (long)row*ldc + col] = f2bf(v);
                } else {   // OMODE 5: fused QKV routing
                    int seg = (col >= 1536) ? 2 : ((col >= 768) ? 1 : 0);
                    int c = col - seg*768;
                    int hh = c >> 6, dd = c & 63;
                    int b = row >> 10, s = row & (S_-1);
                    long hidx = (long)(b*H_ + hh);
                    short* base = (short*)Cv;
                    if (seg < 2) base[(long)seg*QKVS + (hidx*S_ + s)*64 + dd] = f2bf(v);
                    else         base[2L*QKVS + (hidx*64 + dd)*S_ + s] = f2bf(v);
                }
            }
        }
    }
}

// ---------------- 256x256 ring-5 depth-3 counted-vmcnt MFMA GEMM (vocab; best: 165us) ----------------
// R16 A/B: BK=64 ring-2 (64 MFMA/barrier, drain-to-0) = 175us -> worse. Coarse-phase
// floor is ~165us at BK=32/ring-5/depth-3; keep this config.
__global__ __launch_bounds__(512, 1) void k_vgemm(
    const short* __restrict__ A, const short* __restrict__ Bm,
    float* __restrict__ C, const float* __restrict__ bias,
    int N, int K, int lda, int ldb, int ldc)
{
    extern __shared__ short lds[];   // 81920 shorts = 160 KiB
    const int t = threadIdx.x;
    const int lane = t & 63, wave = t >> 6;
    const int wm = wave >> 2, wn = wave & 3;
    const int l15 = lane & 15, l4 = lane >> 4;
    int bx = blockIdx.x, by = blockIdx.y;
    {   // XCD-chunked bijective swizzle
        int lin = by * gridDim.x + bx;
        int nwg = gridDim.x * gridDim.y;
        int xcd = lin & 7, pos = lin >> 3;
        int q = nwg >> 3, r = nwg & 7;
        int lin2 = (xcd < r ? xcd*(q+1) : r*(q+1) + (xcd-r)*q) + pos;
        bx = lin2 % gridDim.x; by = lin2 / gridDim.x;
    }
    const int tile_m = bx * 256, tile_n = by * 256;

    const int c0 = wave*128 + lane;
    const int c1 = c0 + 64;
    const int ar0 = ((c0 >> 6) << 4) + (c0 & 15), ak0 = ((c0 >> 4) & 3) << 3;
    const int ar1 = ((c1 >> 6) << 4) + (c1 & 15), ak1 = ((c1 >> 4) & 3) << 3;
    const short* pa0 = A + (long)(tile_m + ar0)*lda + ak0;
    const short* pa1 = A + (long)(tile_m + ar1)*lda + ak1;
    const short* pb0 = Bm + (long)(tile_n + ar0)*ldb + ak0;
    const short* pb1 = Bm + (long)(tile_n + ar1)*ldb + ak1;
    char* lb = (char*)lds;
    const int wb0 = wave*2048, wb1 = wave*2048 + 1024;

    auto stage = [&](int reg, int s) {
        int k = s << 5;
        char* ab = lb + reg*32768;
        __builtin_amdgcn_global_load_lds((as1vp)(pa0 + k), (as3vp)(ab + wb0),         16, 0, 0);
        __builtin_amdgcn_global_load_lds((as1vp)(pa1 + k), (as3vp)(ab + wb1),         16, 0, 0);
        __builtin_amdgcn_global_load_lds((as1vp)(pb0 + k), (as3vp)(ab + 16384 + wb0), 16, 0, 0);
        __builtin_amdgcn_global_load_lds((as1vp)(pb1 + k), (as3vp)(ab + 16384 + wb1), 16, 0, 0);
    };

    f32x4 acc[8][4] = {};
    const int nks = K >> 5;
    stage(0, 0); stage(1, 1); stage(2, 2);
    const int ard = ((wm*8) << 10) + (l4 << 8) + l15*16;
    const int brd = 16384 + ((wn*4) << 10) + (l4 << 8) + l15*16;

    int reg = 0;
    for (int s = 0; s < nks; s++) {
        if (s + 3 < nks) {
            int r3 = reg + 3; if (r3 >= 5) r3 -= 5;
            stage(r3, s + 3);
        }
        if (s < nks - 3)       asm volatile("s_waitcnt vmcnt(12)" ::: "memory");
        else if (s == nks - 3) asm volatile("s_waitcnt vmcnt(8)"  ::: "memory");
        else if (s == nks - 2) asm volatile("s_waitcnt vmcnt(4)"  ::: "memory");
        else                   asm volatile("s_waitcnt vmcnt(0)"  ::: "memory");
        __builtin_amdgcn_s_barrier();
        const char* rb = lb + reg*32768;
        short8 a[8], b[4];
        #pragma unroll
        for (int fr = 0; fr < 8; fr++) a[fr] = *(const short8*)(rb + ard + (fr << 10));
        #pragma unroll
        for (int fc = 0; fc < 4; fc++) b[fc] = *(const short8*)(rb + brd + (fc << 10));
        __builtin_amdgcn_s_setprio(1);
        #pragma unroll
        for (int fr = 0; fr < 8; fr++)
            #pragma unroll
            for (int fc = 0; fc < 4; fc++)
                acc[fr][fc] = __builtin_amdgcn_mfma_f32_16x16x32_bf16(a[fr], b[fc], acc[fr][fc], 0, 0, 0);
        __builtin_amdgcn_s_setprio(0);
        if (++reg == 5) reg = 0;
    }

    #pragma unroll
    for (int fr = 0; fr < 8; fr++) {
        #pragma unroll
        for (int fc = 0; fc < 4; fc++) {
            int col = tile_n + wn*64 + fc*16 + l15;
            float bv = bias ? bias[col] : 0.f;
            #pragma unroll
            for (int rr = 0; rr < 4; rr++) {
                int row = tile_m + wm*128 + fr*16 + l4*4 + rr;
                C[(long)row*ldc + col] = acc[fr][fc][rr] + bv;
            }
        }
    }
}

// ---------------- flash attention: QK^T/8 + mask-bug + online softmax + PV ----------------
__global__ __launch_bounds__(256) void k_fattn(
    const short* __restrict__ Q, const short* __restrict__ K,
    const short* __restrict__ Vt, const int* __restrict__ mask,
    short* __restrict__ ctx)
{
    __shared__ short plds[4096];   // 4 waves x [16 q][64 kv]
    const int t = threadIdx.x;
    const int lane = t & 63, wave = t >> 6;
    const int l15 = lane & 15, l4 = lane >> 4;
    const int qt = blockIdx.x, z = blockIdx.y;
    const int b = z / H_;
    const long zb = (long)z * S_ * 64;

    const int q = qt*64 + wave*16 + l15;
    short8 aq0 = *(const short8*)(Q + zb + (long)q*64 + l4*8);
    short8 aq1 = *(const short8*)(Q + zb + (long)q*64 + l4*8 + 32);

    float m[4] = {-1e30f, -1e30f, -1e30f, -1e30f};
    float l[4] = {0.f, 0.f, 0.f, 0.f};
    f32x4 O[4] = {};
    short* pw = plds + wave*1024;

    for (int kt = 0; kt < 16; kt++) {
        const int kvb = kt*64;
        f32x4 s[4] = {};
        #pragma unroll
        for (int ct = 0; ct < 4; ct++) {
            const short* kp = K + zb + (long)(kvb + ct*16 + l15)*64 + l4*8;
            short8 b0 = *(const short8*)(kp);
            short8 b1 = *(const short8*)(kp + 32);
            s[ct] = __builtin_amdgcn_mfma_f32_16x16x32_bf16(aq0, b0, s[ct], 0, 0, 0);
            s[ct] = __builtin_amdgcn_mfma_f32_16x16x32_bf16(aq1, b1, s[ct], 0, 0, 0);
        }
        float p[4][4];
        float rmax[4] = {-1e30f, -1e30f, -1e30f, -1e30f};
        #pragma unroll
        for (int ct = 0; ct < 4; ct++) {
            int mv = mask[b*S_ + kvb + ct*16 + l15];
            #pragma unroll
            for (int r = 0; r < 4; r++) {
                float v = (mv == 1) ? -1e9f : s[ct][r]*0.125f;
                p[ct][r] = v;
                rmax[r] = fmaxf(rmax[r], v);
            }
        }
        #pragma unroll
        for (int r = 0; r < 4; r++) {
            float v = rmax[r];
            v = fmaxf(v, __shfl_xor(v, 1));
            v = fmaxf(v, __shfl_xor(v, 2));
            v = fmaxf(v, __shfl_xor(v, 4));
            v = fmaxf(v, __shfl_xor(v, 8));
            float mn = fmaxf(m[r], v);
            float corr = __expf(m[r] - mn);
            float srow = 0.f;
            #pragma unroll
            for (int ct = 0; ct < 4; ct++) {
                float e = __expf(p[ct][r] - mn);
                p[ct][r] = e;
                srow += e;
            }
            srow += __shfl_xor(srow, 1);
            srow += __shfl_xor(srow, 2);
            srow += __shfl_xor(srow, 4);
            srow += __shfl_xor(srow, 8);
            l[r] = l[r]*corr + srow;
            m[r] = mn;
            #pragma unroll
            for (int c2 = 0; c2 < 4; c2++) O[c2][r] *= corr;
        }
        #pragma unroll
        for (int ct = 0; ct < 4; ct++)
            #pragma unroll
            for (int r = 0; r < 4; r++)
                pw[(l4*4 + r)*64 + ct*16 + l15] = f2bf(p[ct][r]);
        asm volatile("s_waitcnt lgkmcnt(0)" ::: "memory");
        __builtin_amdgcn_sched_barrier(0);
        short8 pa0 = *(const short8*)(pw + l15*64 + l4*8);
        short8 pa1 = *(const short8*)(pw + l15*64 + l4*8 + 32);
        #pragma unroll
        for (int c2 = 0; c2 < 4; c2++) {
            const short* vp = Vt + zb + (long)(c2*16 + l15)*S_ + kvb + l4*8;
            short8 v0 = *(const short8*)(vp);
            short8 v1 = *(const short8*)(vp + 32);
            O[c2] = __builtin_amdgcn_mfma_f32_16x16x32_bf16(pa0, v0, O[c2], 0, 0, 0);
            O[c2] = __builtin_amdgcn_mfma_f32_16x16x32_bf16(pa1, v1, O[c2], 0, 0, 0);
        }
    }
    #pragma unroll
    for (int r = 0; r < 4; r++) {
        float inv = 1.f / l[r];
        int qo = qt*64 + wave*16 + l4*4 + r;
        #pragma unroll
        for (int c2 = 0; c2 < 4; c2++)
            ctx[zb + (long)qo*64 + c2*16 + l15] = f2bf(O[c2][r] * inv);
    }
}

// ---------------- mega prep: ALL weight transposes/converts/biases in one launch ----------------
struct WPArgs {
    const float *ow, *wq, *wk, *wv, *wo, *g1, *g2, *f1, *f2, *adj;
    const float *w1, *w3, *w5, *wp, *b1, *b3, *b5, *bq, *bk, *bv;
    short *owt, *wqkvt, *gw1t, *gw2t, *fw1t, *fw2t, *adjb, *wincat, *wincp;
    float *binc, *bqkv, *pooled;
};
__global__ __launch_bounds__(256) void k_wprep(WPArgs a) {
    __shared__ float tile[32][33];
    int blk = blockIdx.x, t = threadIdx.x;
    const float* src; short* dst;
    int R, C, bx, by;
    if (blk < 24000)      { src = a.ow; dst = a.owt; R = 768; C = 32000; bx = blk % 1000; by = blk / 1000; }
    else if (blk < 26304) { int r = blk - 24000; int z = r / 576; r %= 576;
        src = (z == 0) ? a.wq : (z == 1) ? a.wk : (z == 2) ? a.wv : a.wo;
        dst = a.wqkvt + (long)z*589824; R = 768; C = 768; bx = r % 24; by = r / 24; }
    else if (blk < 26592) { int r = blk - 26304; src = a.g1; dst = a.gw1t; R = 768; C = 384;  bx = r % 12; by = r / 12; }
    else if (blk < 26880) { int r = blk - 26592; src = a.g2; dst = a.gw2t; R = 384; C = 768;  bx = r % 24; by = r / 24; }
    else if (blk < 29184) { int r = blk - 26880; src = a.f1; dst = a.fw1t; R = 768; C = 3072; bx = r % 96; by = r / 96; }
    else if (blk < 31488) { int r = blk - 29184; src = a.f2; dst = a.fw2t; R = 3072; C = 768; bx = r % 24; by = r / 24; }
    else if (blk < 33536) {
        long i = ((long)(blk - 31488)*256 + t)*4;
        f32x4 v = *(const f32x4*)(a.adj + i);
        a.adjb[i+0] = f2bf(v.x); a.adjb[i+1] = f2bf(v.y);
        a.adjb[i+2] = f2bf(v.z); a.adjb[i+3] = f2bf(v.w);
        return;
    } else {
        int r = blk - 33536;
        const float* s2; short* d2; long base;
        if (r < 48)       { s2 = a.w1; d2 = a.wincat;          base = (long)r*1024; }
        else if (r < 120) { s2 = a.w3; d2 = a.wincat + 49152;  base = (long)(r-48)*1024; }
        else if (r < 132) { s2 = a.w5; d2 = a.wincat + 122880; base = (long)(r-120)*1024; }
        else if (r < 156) { s2 = a.wp; d2 = a.wincp;           base = (long)(r-132)*1024; }
        else {
            if (t < 176) a.binc[t] = (t < 64) ? a.b1[t] : (t < 160 ? a.b3[t-64] : a.b5[t-160]);
            for (int i = t; i < 2304; i += 256)
                a.bqkv[i] = (i < 768) ? a.bq[i] : (i < 1536 ? a.bk[i-768] : a.bv[i-1536]);
            for (int i = t; i < B_*D_; i += 256)
                a.pooled[i] = 0.f;
            return;
        }
        long i = base + (long)t*4;
        f32x4 v = *(const f32x4*)(s2 + i);
        d2[i+0] = f2bf(v.x); d2[i+1] = f2bf(v.y); d2[i+2] = f2bf(v.z); d2[i+3] = f2bf(v.w);
        return;
    }
    int bc = bx*32, br = by*32;
    int tx = t & 31, ty = t >> 5;
    #pragma unroll
    for (int i = 0; i < 32; i += 8)
        tile[ty + i][tx] = src[(long)(br + ty + i)*C + bc + tx];
    __syncthreads();
    #pragma unroll
    for (int i = 0; i < 32; i += 8)
        dst[(long)(bc + ty + i)*R + br + tx] = f2bf(tile[tx][ty + i]);
}

// ---------------- f32 [R,C] -> bf16 [C,R] transpose-convert (batched, opt. relu) ----------------
template<bool RELU>
__global__ void k_t2b(const float* __restrict__ in, short* __restrict__ out,
                      int R, int C, long sIn, long sOut) {
    __shared__ float tile[32][33];
    int bc = blockIdx.x * 32, br = blockIdx.y * 32;
    const float* ip = in + (long)blockIdx.z * sIn;
    short* op = out + (long)blockIdx.z * sOut;
    int tx = threadIdx.x & 31, ty = threadIdx.x >> 5;
    #pragma unroll
    for (int i = 0; i < 32; i += 8)
        tile[ty + i][tx] = ip[(long)(br + ty + i)*C + bc + tx];
    __syncthreads();
    #pragma unroll
    for (int i = 0; i < 32; i += 8) {
        float v = tile[tx][ty + i];
        if (RELU) v = fmaxf(v, 0.f);
        op[(long)(bc + ty + i)*R + br + tx] = f2bf(v);
    }
}

// ---------------- residual add + LayerNorm (f32 out optional + bf16 out) ----------------
__global__ void k_addln(const float* __restrict__ a, const float* __restrict__ bvec,
                        const float* __restrict__ g, const float* __restrict__ be,
                        float* __restrict__ outf, short* __restrict__ outb) {
    __shared__ float row[D_];
    __shared__ float red[256];
    int n = blockIdx.x, t = threadIdx.x;
    float lsum = 0.f;
    for (int d = t; d < D_; d += 256) {
        float v = a[(long)n*D_ + d] + bvec[(long)n*D_ + d];
        row[d] = v; lsum += v;
    }
    red[t] = lsum; __syncthreads();
    for (int off = 128; off > 0; off >>= 1) {
        if (t < off) red[t] += red[t+off];
        __syncthreads();
    }
    float mean = red[0] / D_; __syncthreads();
    float lvar = 0.f;
    for (int d = t; d < D_; d += 256) { float v = row[d]-mean; lvar += v*v; }
    red[t] = lvar; __syncthreads();
    for (int off = 128; off > 0; off >>= 1) {
        if (t < off) red[t] += red[t+off];
        __syncthreads();
    }
    float rstd = rsqrtf(red[0]/D_ + 1e-5f);
    for (int d = t; d < D_; d += 256) {
        float v = (row[d]-mean)*rstd*g[d] + be[d];
        if (outf) outf[(long)n*D_ + d] = v;
        outb[(long)n*D_ + d] = f2bf(v);
    }
}

// ---------------- mean-pool over sequence (parallel partials + atomics) ----------------
__global__ __launch_bounds__(256) void k_pool(const short* __restrict__ h,
                                              float* __restrict__ pooled) {
    int blk = blockIdx.x;
    int b = blk >> 4, ch = blk & 15;
    int t = threadIdx.x;
    float s0 = 0.f, s1 = 0.f, s2 = 0.f;
    for (int ss = ch*64; ss < ch*64 + 64; ss++) {
        const short* row = h + (long)(b*S_ + ss)*D_;
        s0 += b2fs(row[t]);
        s1 += b2fs(row[t + 256]);
        s2 += b2fs(row[t + 512]);
    }
    atomicAdd(&pooled[b*D_ + t],       s0 * (1.f/S_));
    atomicAdd(&pooled[b*D_ + t + 256], s1 * (1.f/S_));
    atomicAdd(&pooled[b*D_ + t + 512], s2 * (1.f/S_));
}

// ---------------- task head (parallel reduce; block per batch) ----------------
__global__ __launch_bounds__(256) void k_task(const float* __restrict__ pooled,
                                              const float* __restrict__ tw,
                                              const float* __restrict__ tb,
                                              float* __restrict__ out) {
    __shared__ float red[256][3];
    int b = blockIdx.x, t = threadIdx.x;
    float a0 = 0.f, a1 = 0.f, a2 = 0.f;
    for (int d = t; d < D_; d += 256) {
        float p = pooled[b*D_ + d];
        a0 += p*tw[d*3+0]; a1 += p*tw[d*3+1]; a2 += p*tw[d*3+2];
    }
    red[t][0] = a0; red[t][1] = a1; red[t][2] = a2;
    __syncthreads();
    for (int off = 128; off > 0; off >>= 1) {
        if (t < off) {
            red[t][0] += red[t+off][0];
            red[t][1] += red[t+off][1];
            red[t][2] += red[t+off][2];
        }
        __syncthreads();
    }
    if (t < 3) out[(long)NTOK*V_ + b*3 + t] = red[0][t] + tb[t];
}

extern "C" void kernel_launch(void* const* d_in, const int* in_sizes, int n_in,
                              void* d_out, int out_size, void* d_ws, size_t ws_size,
                              hipStream_t stream) {
    const int*   x      = (const int*)d_in[0];
    const int*   amask  = (const int*)d_in[1];
    const float* adj    = (const float*)d_in[2];
    const float* emb    = (const float*)d_in[3];
    const float* inc1_w = (const float*)d_in[4];  const float* inc1_b = (const float*)d_in[5];
    const float* inc3a_w= (const float*)d_in[6];  const float* inc3a_b= (const float*)d_in[7];
    const float* inc3b_w= (const float*)d_in[8];  const float* inc3b_b= (const float*)d_in[9];
    const float* inc5a_w= (const float*)d_in[10]; const float* inc5a_b= (const float*)d_in[11];
    const float* inc5b_w= (const float*)d_in[12]; const float* inc5b_b= (const float*)d_in[13];
    const float* incp_w = (const float*)d_in[14]; const float* incp_b = (const float*)d_in[15];
    const float* q_rot  = (const float*)d_in[16]; const float* q_ent  = (const float*)d_in[17];
    const float* gnn_w1 = (const float*)d_in[18]; const float* gnn_b1 = (const float*)d_in[19];
    const float* gnn_w2 = (const float*)d_in[20]; const float* gnn_b2 = (const float*)d_in[21];
    const float* wq = (const float*)d_in[22]; const float* bq = (const float*)d_in[23];
    const float* wk = (const float*)d_in[24]; const float* bk = (const float*)d_in[25];
    const float* wv = (const float*)d_in[26]; const float* bv = (const float*)d_in[27];
    const float* wo = (const float*)d_in[28]; const float* bo = (const float*)d_in[29];
    const float* ff_w1 = (const float*)d_in[30]; const float* ff_b1 = (const float*)d_in[31];
    const float* ff_w2 = (const float*)d_in[32]; const float* ff_b2 = (const float*)d_in[33];
    const float* ln1_g = (const float*)d_in[34]; const float* ln1_b = (const float*)d_in[35];
    const float* ln2_g = (const float*)d_in[36]; const float* ln2_b = (const float*)d_in[37];
    const float* out_w = (const float*)d_in[38]; const float* out_b = (const float*)d_in[39];
    const float* task_w= (const float*)d_in[40]; const float* task_b= (const float*)d_in[41];

    // d_out arena (f32 slot offsets; non-overlapping; dead before vocab GEMM).
    // Zero-spans are contiguous: [CO..h1f) = [6636032, 8569344); [gbf..ao2 end) = [24363520, 28295680).
    float* F = (float*)d_out;
    short* wqkvt = (short*)(F + 0L);
    short* gw1t  = (short*)(F + 1179648L);
    short* gw2t  = (short*)(F + 1327104L);
    short* fw1t  = (short*)(F + 1474560L);
    short* fw2t  = (short*)(F + 2654208L);
    short* wincat= (short*)(F + 3833856L);
    short* wincp = (short*)(F + 3950592L);
    float* binc  = F + 4012032L;
    float* bqkv  = F + 4012288L;
    short* adjb  = (short*)(F + 4014592L);
    short* h0b   = (short*)(F + 5063168L);
    short* mpb   = (short*)(F + 5849600L);
    float* CO    = F + 6636032L;    // 360448 slots
    float* h1f   = F + 6996480L;    // 1572864 slots
    short* h1t   = (short*)(F + 8569344L);
    short* t1b   = (short*)(F + 9355776L);
    short* gt    = (short*)(F + 10928640L);
    short* t2bv  = (short*)(F + 11321856L);
    float* h2f   = F + 11715072L;
    short* h2b   = (short*)(F + 13287936L);
    short* Qh    = (short*)(F + 14074368L);   // Kh, Vt contiguous (OMODE5)
    short* Kh    = (short*)(F + 14860800L);
    short* Vt    = (short*)(F + 15647232L);   // +pad for B-OOB
    short* ctxh  = (short*)(F + 16499200L);
    float* hlnf  = F + 18858496L;
    short* hlnb  = (short*)(F + 20431360L);
    short* ff1b  = (short*)(F + 21217792L);   // ends 24363520
    float* gbf   = F + 24363520L;   // 786432 slots
    float* ao    = F + 25149952L;   // 1572864 slots
    float* ao2   = F + 26722816L;   // 1572864 slots; ends 28295680 < 65536000

    // d_ws
    char* W = (char*)d_ws;
    short* hfb    = (short*)(W + 0);
    float* pooled = (float*)(W + 3145728);
    short* owt    = (short*)(W + 3151872);

    auto gb = [](int M, int N, int Z) { return dim3((unsigned)(M/128), (unsigned)((N+127)/128), (unsigned)Z); };

    (void)hipFuncSetAttribute((const void*)k_vgemm, hipFuncAttributeMaxDynamicSharedMemorySize, 163840);

    // 0a. zero atomic targets (2 merged memsets; pooled zeroed inside k_wprep)
    (void)hipMemsetAsync(CO,  0, (size_t)(360448 + 1572864)*4, stream);
    (void)hipMemsetAsync(gbf, 0, (size_t)(786432 + 2*1572864)*4, stream);

    // 0b. ALL one-time converts/transposes/bias concats in ONE launch
    {
        WPArgs wa;
        wa.ow = out_w; wa.wq = wq; wa.wk = wk; wa.wv = wv; wa.wo = wo;
        wa.g1 = gnn_w1; wa.g2 = gnn_w2; wa.f1 = ff_w1; wa.f2 = ff_w2; wa.adj = adj;
        wa.w1 = inc1_w; wa.w3 = inc3a_w; wa.w5 = inc5a_w; wa.wp = incp_w;
        wa.b1 = inc1_b; wa.b3 = inc3a_b; wa.b5 = inc5a_b;
        wa.bq = bq; wa.bk = bk; wa.bv = bv;
        wa.owt = owt; wa.wqkvt = wqkvt; wa.gw1t = gw1t; wa.gw2t = gw2t;
        wa.fw1t = fw1t; wa.fw2t = fw2t; wa.adjb = adjb;
        wa.wincat = wincat; wa.wincp = wincp; wa.binc = binc; wa.bqkv = bqkv;
        wa.pooled = pooled;
        k_wprep<<<dim3(33693), 256, 0, stream>>>(wa);
    }

    // 1. embedding + maxpool fused (bf16)
    k_embed2<<<dim3(NTOK), dim3(256), 0, stream>>>(x, emb, h0b, mpb);

    // 2. inception 1x1 GEMMs, split-K for occupancy
    k_bgemm<0,0,false,4><<<gb(NTOK, 176, 4), 256, 0, stream>>>(
        h0b, wincat, CO, nullptr, binc, 1.f, 176, D_, D_, D_, 176, 0, 0, 0);
    k_bgemm<0,0,false,8><<<gb(NTOK, 32, 8), 256, 0, stream>>>(
        mpb, wincp, h1f + 224, nullptr, incp_b, 1.f, 32, D_, D_, D_, NQ_, 0, 0, 0);

    // 3. fused conv3/conv5/copy/quantum x2
    k_mix<<<dim3(NTOK), dim3(256), 0, stream>>>(
        CO, inc3b_w, inc3b_b, inc5b_w, inc5b_b, q_rot, q_ent, h1f);

    // 4. GNN
    k_t2b<false><<<dim3(24,32,2), 256, 0, stream>>>(h1f, h1t, S_, NQ_, (long)S_*NQ_, (long)S_*NQ_);
    k_bgemm<0,1,false><<<gb(S_, NQ_, B_), 256, 0, stream>>>(
        adjb, h1t, t1b, nullptr, nullptr, 1.f, NQ_, S_, S_, S_, NQ_,
        (long)S_*S_, (long)NQ_*S_, (long)S_*NQ_);
    k_bgemm<0,0,false,4><<<gb(NTOK, 384, 4), 256, 0, stream>>>(
        t1b, gw1t, gbf, nullptr, gnn_b1, 1.f, 384, D_, D_, D_, 384, 0, 0, 0);
    k_t2b<true><<<dim3(12,32,2), 256, 0, stream>>>(gbf, gt, S_, 384, (long)S_*384, (long)S_*384);
    k_bgemm<0,1,false><<<gb(S_, 384, B_), 256, 0, stream>>>(
        adjb, gt, t2bv, nullptr, nullptr, 1.f, 384, S_, S_, S_, 384,
        (long)S_*S_, (long)384*S_, (long)S_*384);
    k_bgemm<0,2,false><<<gb(NTOK, D_, 1), 256, 0, stream>>>(
        t2bv, gw2t, h2b, h2f, gnn_b2, 1.f, D_, 384, 384, 384, D_, 0, 0, 0);

    // 5. attention: fused QKV -> flash attention -> WO -> add+LN
    k_bgemm<0,5,false><<<gb(NTOK, 3*D_, 1), 256, 0, stream>>>(
        h2b, wqkvt, Qh, nullptr, bqkv, 1.f, 3*D_, D_, D_, D_, 0, 0, 0, 0);
    k_fattn<<<dim3(S_/64, B_*H_), 256, 0, stream>>>(Qh, Kh, Vt, amask, ctxh);
    k_bgemm<1,0,false,2><<<gb(NTOK, D_, 2), 256, 0, stream>>>(
        ctxh, wqkvt + 3L*589824, ao, nullptr, bo, 1.f, D_, D_, D_, D_, D_, 0, 0, 0);
    k_addln<<<dim3(NTOK), dim3(256), 0, stream>>>(h2f, ao, ln1_g, ln1_b, hlnf, hlnb);

    // 6. FFN
    k_bgemm<0,1,true><<<gb(NTOK, 4*D_, 1), 256, 0, stream>>>(
        hlnb, fw1t, ff1b, nullptr, ff_b1, 1.f, 4*D_, D_, D_, D_, 4*D_, 0, 0, 0);
    k_bgemm<0,0,false,4><<<gb(NTOK, D_, 4), 256, 0, stream>>>(
        ff1b, fw2t, ao2, nullptr, ff_b2, 1.f, D_, 4*D_, 4*D_, 4*D_, D_, 0, 0, 0);
    k_addln<<<dim3(NTOK), dim3(256), 0, stream>>>(hlnf, ao2, ln2_g, ln2_b, nullptr, hfb);

    // 7. heads: parallel pool, vocab GEMM (256^2 ring-5 depth-3), parallel task
    k_pool<<<dim3(B_*16), dim3(256), 0, stream>>>(hfb, pooled);
    k_vgemm<<<dim3(NTOK/256, V_/256, 1), dim3(512), 163840, stream>>>(
        hfb, owt, (float*)d_out, out_b, V_, D_, D_, D_, V_);
    k_task<<<dim3(B_), dim3(256), 0, stream>>>(pooled, task_w, task_b, (float*)d_out);
}

// Round 19
// 634.747 us; speedup vs baseline: 1.0242x; 1.0022x over previous
//
#include <hip/hip_runtime.h>
#include <hip/hip_bf16.h>

#define B_ 2
#define S_ 1024
#define D_ 768
#define H_ 12
#define HD_ 64
#define V_ 32000
#define NQ_ 768
#define NTOK (B_*S_)
#define QKVS 1572864L   // shorts per Q/K/V segment [B,H,S,64]

typedef __attribute__((ext_vector_type(8))) short short8;
typedef __attribute__((ext_vector_type(4))) short s16x4;
typedef __attribute__((ext_vector_type(4))) float f32x4;
typedef __attribute__((ext_vector_type(4))) int i32x4;

typedef const __attribute__((address_space(1))) void* as1vp;
typedef __attribute__((address_space(3))) void* as3vp;

__device__ __forceinline__ short f2bf(float f) {
    union { float f; unsigned u; } v; v.f = f;
    unsigned r = (v.u + 0x7FFFu + ((v.u >> 16) & 1u)) >> 16;
    return (short)r;
}
__device__ __forceinline__ float b2fs(short s) {
    union { unsigned u; float f; } v; v.u = ((unsigned)(unsigned short)s) << 16;
    return v.f;
}

// ---------------- embedding + maxpool3 fused (vectorized f32x4 / s16x4) ----------------
__global__ __launch_bounds__(192) void k_embed2(
    const int* __restrict__ x, const float* __restrict__ emb,
    short* __restrict__ h0b, short* __restrict__ mpb) {
    int n = blockIdx.x; int s = n & (S_-1);
    int r0 = x[n];
    int rm = (s > 0)      ? x[n-1] : -1;
    int rp = (s < S_-1)   ? x[n+1] : -1;
    int d = threadIdx.x * 4;   // 192 threads x 4 = 768
    f32x4 e = *(const f32x4*)(emb + (long)r0*D_ + d);
    f32x4 m = e;
    if (rm >= 0) {
        f32x4 a = *(const f32x4*)(emb + (long)rm*D_ + d);
        #pragma unroll
        for (int j = 0; j < 4; j++) m[j] = fmaxf(m[j], a[j]);
    }
    if (rp >= 0) {
        f32x4 a = *(const f32x4*)(emb + (long)rp*D_ + d);
        #pragma unroll
        for (int j = 0; j < 4; j++) m[j] = fmaxf(m[j], a[j]);
    }
    s16x4 ev, mv;
    #pragma unroll
    for (int j = 0; j < 4; j++) { ev[j] = f2bf(e[j]); mv[j] = f2bf(m[j]); }
    *(s16x4*)(h0b + (long)n*D_ + d) = ev;
    *(s16x4*)(mpb + (long)n*D_ + d) = mv;
}

// ---------------- fused conv3+conv5+copy+incp-merge+quantum x2 ----------------
__global__ __launch_bounds__(256) void k_mix(
    const float* __restrict__ CO, const float* __restrict__ c3w,
    const float* __restrict__ c3b, const float* __restrict__ c5w,
    const float* __restrict__ c5b, const float* __restrict__ q_rot,
    const float* __restrict__ q_ent, float* __restrict__ h1f)
{
    __shared__ float co[5][176];
    __shared__ float ta[NQ_];
    __shared__ float tb[NQ_];
    int n = blockIdx.x; int s = n & (S_-1);
    int t = threadIdx.x;
    for (int idx = t; idx < 5*176; idx += 256) {
        int dr = idx / 176 - 2, c = idx % 176;
        int ss = s + dr;
        co[idx/176][c] = (ss >= 0 && ss < S_) ? CO[(long)(n + dr)*176 + c] : 0.f;
    }
    for (int d = 256 + t; d < NQ_; d += 256) ta[d] = 0.f;
    __syncthreads();
    if (t < 64) {
        ta[t] = co[2][t];
    } else if (t < 192) {
        int o = t - 64;
        float acc = c3b[o];
        #pragma unroll
        for (int k = 0; k < 3; k++)
            for (int i = 0; i < 96; i++)
                acc += co[1+k][64+i] * c3w[(o*96+i)*3 + k];
        ta[t] = acc;
    } else if (t < 224) {
        int o = t - 192;
        float acc = c5b[o];
        #pragma unroll
        for (int k = 0; k < 5; k++)
            for (int i = 0; i < 16; i++)
                acc += co[k][160+i] * c5w[(o*16+i)*5 + k];
        ta[t] = acc;
    } else {
        ta[t] = h1f[(long)n*NQ_ + t];
    }
    __syncthreads();
    #pragma unroll
    for (int layer = 0; layer < 2; layer++) {
        const float* rot = q_rot + (long)layer*NQ_*3;
        const float* ent = q_ent + (long)layer*(NQ_-1);
        for (int q = t; q < NQ_; q += 256) {
            float hv = ta[q];
            tb[q] = __sinf(hv + rot[q*3]) + __sinf(hv + rot[q*3+1]) + __sinf(hv + rot[q*3+2]);
        }
        __syncthreads();
        for (int q = t; q < NQ_; q += 256) {
            float v;
            if (q == NQ_-1) v = 0.f;
            else {
                int qm = (q == 0) ? (NQ_-1) : (q-1);
                v = tb[q]*__sinf(ent[q]) + tb[qm]*__cosf(ent[q]);
            }
            ta[q] = v;
        }
        __syncthreads();
    }
    for (int q = t; q < NQ_; q += 256) h1f[(long)n*NQ_ + q] = ta[q];
}

// ---------------- bf16 MFMA GEMM (128x128, 2-phase, optional split-K) ----------------
template<int AMODE, int OMODE, bool RELU, int KSPLIT = 1>
__global__ __launch_bounds__(256) void k_bgemm(
    const short* __restrict__ A, const short* __restrict__ Bm,
    void* __restrict__ Cv, float* __restrict__ C2,
    const float* __restrict__ bias, float scale,
    int N, int K, int lda, int ldb, int ldc,
    long sA, long sB, long sC)
{
    __shared__ short lds[2][8192];
    const int t = threadIdx.x;
    const int lane = t & 63, wave = t >> 6;
    const int wm = wave >> 1, wn = wave & 1;
    const int l15 = lane & 15, l4 = lane >> 4;

    int bx = blockIdx.x, by = blockIdx.y;
    if (KSPLIT == 1 && gridDim.z == 1) {
        int lin = by * gridDim.x + bx;
        int nwg = gridDim.x * gridDim.y;
        int xcd = lin & 7, pos = lin >> 3;
        int q = nwg >> 3, r = nwg & 7;
        int lin2 = (xcd < r ? xcd*(q+1) : r*(q+1) + (xcd-r)*q) + pos;
        bx = lin2 % gridDim.x;
        by = lin2 / gridDim.x;
    }
    const int tile_m = bx * 128, tile_n = by * 128;
    const int kz = (KSPLIT > 1) ? blockIdx.z : 0;
    const int Keff = K / KSPLIT;
    const int kbase = kz * Keff;
    const long aoff = (KSPLIT > 1) ? 0 : (long)blockIdx.z * sA;
    const long boff = (KSPLIT > 1) ? 0 : (long)blockIdx.z * sB;
    const long coff = (KSPLIT > 1) ? 0 : (long)blockIdx.z * sC;

    const int cA0 = t, cA1 = t + 256;
    const int arow0 = tile_m + ((cA0 >> 6) << 4) + (cA0 & 15);
    const int arow1 = tile_m + ((cA1 >> 6) << 4) + (cA1 & 15);
    const int akb0 = ((cA0 >> 4) & 3) * 8;
    const int akb1 = ((cA1 >> 4) & 3) * 8;
    const int bcol0 = tile_n + (((cA0 >> 4) & 7) << 4) + (cA0 & 15);
    const int bcol1 = tile_n + (((cA1 >> 4) & 7) << 4) + (cA1 & 15);
    const int bkb0 = (cA0 >> 7) * 8;
    const int bkb1 = (cA1 >> 7) * 8;
    const short* bp0 = Bm + boff + (long)bcol0*ldb + bkb0 + kbase;
    const short* bp1 = Bm + boff + (long)bcol1*ldb + bkb1 + kbase;
    const short* ap0 = nullptr; const short* ap1 = nullptr;
    long abase0 = 0, abase1 = 0;
    if (AMODE == 0) {
        ap0 = A + aoff + (long)arow0*lda + akb0 + kbase;
        ap1 = A + aoff + (long)arow1*lda + akb1 + kbase;
    } else {
        abase0 = ((long)((arow0 >> 10)*H_) * S_ + (arow0 & (S_-1))) * 64;
        abase1 = ((long)((arow1 >> 10)*H_) * S_ + (arow1 & (S_-1))) * 64;
    }
    const int wb = wave * 1024;

    auto stage = [&](int buf, int k0) {
        char* lb = (char*)&lds[buf][0];
        const short *a0, *a1;
        if (AMODE == 0) { a0 = ap0 + k0; a1 = ap1 + k0; }
        else {
            int ka0 = kbase + k0 + akb0, ka1 = kbase + k0 + akb1;
            a0 = A + abase0 + (long)(ka0 >> 6)*(S_*64) + (ka0 & 63);
            a1 = A + abase1 + (long)(ka1 >> 6)*(S_*64) + (ka1 & 63);
        }
        __builtin_amdgcn_global_load_lds((as1vp)a0,          (as3vp)(lb + wb),          16, 0, 0);
        __builtin_amdgcn_global_load_lds((as1vp)a1,          (as3vp)(lb + 4096 + wb),   16, 0, 0);
        __builtin_amdgcn_global_load_lds((as1vp)(bp0 + k0),  (as3vp)(lb + 8192 + wb),   16, 0, 0);
        __builtin_amdgcn_global_load_lds((as1vp)(bp1 + k0),  (as3vp)(lb + 12288 + wb),  16, 0, 0);
    };

    f32x4 acc[4][4] = {};
    const int nk = Keff >> 5;
    stage(0, 0);
    __syncthreads();
    int cur = 0;
    for (int ks = 0; ks < nk; ks++) {
        if (ks + 1 < nk) stage(cur ^ 1, (ks + 1) << 5);
        short8 af[4], bfv[4];
        const short* lb = &lds[cur][0];
        #pragma unroll
        for (int m = 0; m < 4; m++)
            af[m] = *(const short8*)(lb + (wm*4 + m)*512 + l4*128 + l15*8);
        #pragma unroll
        for (int n = 0; n < 4; n++)
            bfv[n] = *(const short8*)(lb + 4096 + l4*1024 + (wn*4 + n)*128 + l15*8);
        #pragma unroll
        for (int m = 0; m < 4; m++)
            #pragma unroll
            for (int n = 0; n < 4; n++)
                acc[m][n] = __builtin_amdgcn_mfma_f32_16x16x32_bf16(af[m], bfv[n], acc[m][n], 0, 0, 0);
        __syncthreads();
        cur ^= 1;
    }

    #pragma unroll
    for (int m = 0; m < 4; m++) {
        #pragma unroll
        for (int n = 0; n < 4; n++) {
            int col = tile_n + wn*64 + n*16 + l15;
            if (col >= N) continue;
            float bv = (bias && (KSPLIT == 1 || kz == 0)) ? bias[col] : 0.f;
            #pragma unroll
            for (int r = 0; r < 4; r++) {
                int row = tile_m + wm*64 + m*16 + l4*4 + r;
                float v = acc[m][n][r] * scale + bv;
                if (RELU) v = fmaxf(v, 0.f);
                if (OMODE == 0) {
                    if (KSPLIT > 1)
                        atomicAdd(&((float*)Cv)[(long)row*ldc + col], v);
                    else
                        ((float*)Cv)[coff + (long)row*ldc + col] = v;
                } else if (OMODE == 1) {
                    ((short*)Cv)[coff + (long)row*ldc + col] = f2bf(v);
                } else if (OMODE == 2) {
                    C2[coff + (long)row*ldc + col] = v;
                    ((short*)Cv)[coff + (long)row*ldc + col] = f2bf(v);
                } else {   // OMODE 5: fused QKV routing
                    int seg = (col >= 1536) ? 2 : ((col >= 768) ? 1 : 0);
                    int c = col - seg*768;
                    int hh = c >> 6, dd = c & 63;
                    int b = row >> 10, s = row & (S_-1);
                    long hidx = (long)(b*H_ + hh);
                    short* base = (short*)Cv;
                    if (seg < 2) base[(long)seg*QKVS + (hidx*S_ + s)*64 + dd] = f2bf(v);
                    else         base[2L*QKVS + (hidx*64 + dd)*S_ + s] = f2bf(v);
                }
            }
        }
    }
}

// ---------------- 256x256 ring-5 depth-4 counted-vmcnt MFMA GEMM (vocab) ----------------
// Coarse-phase floor established across R7-R16: 165us at BK=32/ring-5. Depth 3->4:
// stage(s+4) targets region (s-1)%5; every wave's region-(s-1) ds_reads completed
// before its barrier(s) arrival (reads precede the pre-barrier MFMAs that consume
// them), and stage(s+4) is issued only after barrier(s) -> race-free.
// Steady-state wait vmcnt(16) = 4 regions x 4 loads in flight.
__global__ __launch_bounds__(512, 1) void k_vgemm(
    const short* __restrict__ A, const short* __restrict__ Bm,
    float* __restrict__ C, const float* __restrict__ bias,
    int N, int K, int lda, int ldb, int ldc)
{
    extern __shared__ short lds[];   // 81920 shorts = 160 KiB
    const int t = threadIdx.x;
    const int lane = t & 63, wave = t >> 6;
    const int wm = wave >> 2, wn = wave & 3;
    const int l15 = lane & 15, l4 = lane >> 4;
    int bx = blockIdx.x, by = blockIdx.y;
    {   // XCD-chunked bijective swizzle
        int lin = by * gridDim.x + bx;
        int nwg = gridDim.x * gridDim.y;
        int xcd = lin & 7, pos = lin >> 3;
        int q = nwg >> 3, r = nwg & 7;
        int lin2 = (xcd < r ? xcd*(q+1) : r*(q+1) + (xcd-r)*q) + pos;
        bx = lin2 % gridDim.x; by = lin2 / gridDim.x;
    }
    const int tile_m = bx * 256, tile_n = by * 256;

    const int c0 = wave*128 + lane;
    const int c1 = c0 + 64;
    const int ar0 = ((c0 >> 6) << 4) + (c0 & 15), ak0 = ((c0 >> 4) & 3) << 3;
    const int ar1 = ((c1 >> 6) << 4) + (c1 & 15), ak1 = ((c1 >> 4) & 3) << 3;
    const short* pa0 = A + (long)(tile_m + ar0)*lda + ak0;
    const short* pa1 = A + (long)(tile_m + ar1)*lda + ak1;
    const short* pb0 = Bm + (long)(tile_n + ar0)*ldb + ak0;
    const short* pb1 = Bm + (long)(tile_n + ar1)*ldb + ak1;
    char* lb = (char*)lds;
    const int wb0 = wave*2048, wb1 = wave*2048 + 1024;

    auto stage = [&](int reg, int s) {
        int k = s << 5;
        char* ab = lb + reg*32768;
        __builtin_amdgcn_global_load_lds((as1vp)(pa0 + k), (as3vp)(ab + wb0),         16, 0, 0);
        __builtin_amdgcn_global_load_lds((as1vp)(pa1 + k), (as3vp)(ab + wb1),         16, 0, 0);
        __builtin_amdgcn_global_load_lds((as1vp)(pb0 + k), (as3vp)(ab + 16384 + wb0), 16, 0, 0);
        __builtin_amdgcn_global_load_lds((as1vp)(pb1 + k), (as3vp)(ab + 16384 + wb1), 16, 0, 0);
    };

    f32x4 acc[8][4] = {};
    const int nks = K >> 5;
    stage(0, 0); stage(1, 1); stage(2, 2); stage(3, 3);
    const int ard = ((wm*8) << 10) + (l4 << 8) + l15*16;
    const int brd = 16384 + ((wn*4) << 10) + (l4 << 8) + l15*16;

    int reg = 0;
    for (int s = 0; s < nks; s++) {
        if (s + 4 < nks) {
            int r4 = reg + 4; if (r4 >= 5) r4 -= 5;
            stage(r4, s + 4);
        }
        if (s < nks - 4)       asm volatile("s_waitcnt vmcnt(16)" ::: "memory");
        else if (s == nks - 4) asm volatile("s_waitcnt vmcnt(12)" ::: "memory");
        else if (s == nks - 3) asm volatile("s_waitcnt vmcnt(8)"  ::: "memory");
        else if (s == nks - 2) asm volatile("s_waitcnt vmcnt(4)"  ::: "memory");
        else                   asm volatile("s_waitcnt vmcnt(0)"  ::: "memory");
        __builtin_amdgcn_s_barrier();
        const char* rb = lb + reg*32768;
        short8 a[8], b[4];
        #pragma unroll
        for (int fr = 0; fr < 8; fr++) a[fr] = *(const short8*)(rb + ard + (fr << 10));
        #pragma unroll
        for (int fc = 0; fc < 4; fc++) b[fc] = *(const short8*)(rb + brd + (fc << 10));
        __builtin_amdgcn_s_setprio(1);
        #pragma unroll
        for (int fr = 0; fr < 8; fr++)
            #pragma unroll
            for (int fc = 0; fc < 4; fc++)
                acc[fr][fc] = __builtin_amdgcn_mfma_f32_16x16x32_bf16(a[fr], b[fc], acc[fr][fc], 0, 0, 0);
        __builtin_amdgcn_s_setprio(0);
        if (++reg == 5) reg = 0;
    }

    #pragma unroll
    for (int fr = 0; fr < 8; fr++) {
        #pragma unroll
        for (int fc = 0; fc < 4; fc++) {
            int col = tile_n + wn*64 + fc*16 + l15;
            float bv = bias ? bias[col] : 0.f;
            #pragma unroll
            for (int rr = 0; rr < 4; rr++) {
                int row = tile_m + wm*128 + fr*16 + l4*4 + rr;
                C[(long)row*ldc + col] = acc[fr][fc][rr] + bv;
            }
        }
    }
}

// ---------------- flash attention: QK^T/8 + mask-bug + online softmax + PV ----------------
__global__ __launch_bounds__(256) void k_fattn(
    const short* __restrict__ Q, const short* __restrict__ K,
    const short* __restrict__ Vt, const int* __restrict__ mask,
    short* __restrict__ ctx)
{
    __shared__ short plds[4096];   // 4 waves x [16 q][64 kv]
    const int t = threadIdx.x;
    const int lane = t & 63, wave = t >> 6;
    const int l15 = lane & 15, l4 = lane >> 4;
    const int qt = blockIdx.x, z = blockIdx.y;
    const int b = z / H_;
    const long zb = (long)z * S_ * 64;

    const int q = qt*64 + wave*16 + l15;
    short8 aq0 = *(const short8*)(Q + zb + (long)q*64 + l4*8);
    short8 aq1 = *(const short8*)(Q + zb + (long)q*64 + l4*8 + 32);

    float m[4] = {-1e30f, -1e30f, -1e30f, -1e30f};
    float l[4] = {0.f, 0.f, 0.f, 0.f};
    f32x4 O[4] = {};
    short* pw = plds + wave*1024;

    for (int kt = 0; kt < 16; kt++) {
        const int kvb = kt*64;
        f32x4 s[4] = {};
        #pragma unroll
        for (int ct = 0; ct < 4; ct++) {
            const short* kp = K + zb + (long)(kvb + ct*16 + l15)*64 + l4*8;
            short8 b0 = *(const short8*)(kp);
            short8 b1 = *(const short8*)(kp + 32);
            s[ct] = __builtin_amdgcn_mfma_f32_16x16x32_bf16(aq0, b0, s[ct], 0, 0, 0);
            s[ct] = __builtin_amdgcn_mfma_f32_16x16x32_bf16(aq1, b1, s[ct], 0, 0, 0);
        }
        float p[4][4];
        float rmax[4] = {-1e30f, -1e30f, -1e30f, -1e30f};
        #pragma unroll
        for (int ct = 0; ct < 4; ct++) {
            int mv = mask[b*S_ + kvb + ct*16 + l15];
            #pragma unroll
            for (int r = 0; r < 4; r++) {
                float v = (mv == 1) ? -1e9f : s[ct][r]*0.125f;
                p[ct][r] = v;
                rmax[r] = fmaxf(rmax[r], v);
            }
        }
        #pragma unroll
        for (int r = 0; r < 4; r++) {
            float v = rmax[r];
            v = fmaxf(v, __shfl_xor(v, 1));
            v = fmaxf(v, __shfl_xor(v, 2));
            v = fmaxf(v, __shfl_xor(v, 4));
            v = fmaxf(v, __shfl_xor(v, 8));
            float mn = fmaxf(m[r], v);
            float corr = __expf(m[r] - mn);
            float srow = 0.f;
            #pragma unroll
            for (int ct = 0; ct < 4; ct++) {
                float e = __expf(p[ct][r] - mn);
                p[ct][r] = e;
                srow += e;
            }
            srow += __shfl_xor(srow, 1);
            srow += __shfl_xor(srow, 2);
            srow += __shfl_xor(srow, 4);
            srow += __shfl_xor(srow, 8);
            l[r] = l[r]*corr + srow;
            m[r] = mn;
            #pragma unroll
            for (int c2 = 0; c2 < 4; c2++) O[c2][r] *= corr;
        }
        #pragma unroll
        for (int ct = 0; ct < 4; ct++)
            #pragma unroll
            for (int r = 0; r < 4; r++)
                pw[(l4*4 + r)*64 + ct*16 + l15] = f2bf(p[ct][r]);
        asm volatile("s_waitcnt lgkmcnt(0)" ::: "memory");
        __builtin_amdgcn_sched_barrier(0);
        short8 pa0 = *(const short8*)(pw + l15*64 + l4*8);
        short8 pa1 = *(const short8*)(pw + l15*64 + l4*8 + 32);
        #pragma unroll
        for (int c2 = 0; c2 < 4; c2++) {
            const short* vp = Vt + zb + (long)(c2*16 + l15)*S_ + kvb + l4*8;
            short8 v0 = *(const short8*)(vp);
            short8 v1 = *(const short8*)(vp + 32);
            O[c2] = __builtin_amdgcn_mfma_f32_16x16x32_bf16(pa0, v0, O[c2], 0, 0, 0);
            O[c2] = __builtin_amdgcn_mfma_f32_16x16x32_bf16(pa1, v1, O[c2], 0, 0, 0);
        }
    }
    #pragma unroll
    for (int r = 0; r < 4; r++) {
        float inv = 1.f / l[r];
        int qo = qt*64 + wave*16 + l4*4 + r;
        #pragma unroll
        for (int c2 = 0; c2 < 4; c2++)
            ctx[zb + (long)qo*64 + c2*16 + l15] = f2bf(O[c2][r] * inv);
    }
}

// ---------------- mega prep: ALL weight transposes/converts/biases in one launch ----------------
struct WPArgs {
    const float *ow, *wq, *wk, *wv, *wo, *g1, *g2, *f1, *f2, *adj;
    const float *w1, *w3, *w5, *wp, *b1, *b3, *b5, *bq, *bk, *bv;
    short *owt, *wqkvt, *gw1t, *gw2t, *fw1t, *fw2t, *adjb, *wincat, *wincp;
    float *binc, *bqkv, *pooled;
};
__global__ __launch_bounds__(256) void k_wprep(WPArgs a) {
    __shared__ float tile[32][33];
    int blk = blockIdx.x, t = threadIdx.x;
    const float* src; short* dst;
    int R, C, bx, by;
    if (blk < 24000)      { src = a.ow; dst = a.owt; R = 768; C = 32000; bx = blk % 1000; by = blk / 1000; }
    else if (blk < 26304) { int r = blk - 24000; int z = r / 576; r %= 576;
        src = (z == 0) ? a.wq : (z == 1) ? a.wk : (z == 2) ? a.wv : a.wo;
        dst = a.wqkvt + (long)z*589824; R = 768; C = 768; bx = r % 24; by = r / 24; }
    else if (blk < 26592) { int r = blk - 26304; src = a.g1; dst = a.gw1t; R = 768; C = 384;  bx = r % 12; by = r / 12; }
    else if (blk < 26880) { int r = blk - 26592; src = a.g2; dst = a.gw2t; R = 384; C = 768;  bx = r % 24; by = r / 24; }
    else if (blk < 29184) { int r = blk - 26880; src = a.f1; dst = a.fw1t; R = 768; C = 3072; bx = r % 96; by = r / 96; }
    else if (blk < 31488) { int r = blk - 29184; src = a.f2; dst = a.fw2t; R = 3072; C = 768; bx = r % 24; by = r / 24; }
    else if (blk < 33536) {
        long i = ((long)(blk - 31488)*256 + t)*4;
        f32x4 v = *(const f32x4*)(a.adj + i);
        a.adjb[i+0] = f2bf(v.x); a.adjb[i+1] = f2bf(v.y);
        a.adjb[i+2] = f2bf(v.z); a.adjb[i+3] = f2bf(v.w);
        return;
    } else {
        int r = blk - 33536;
        const float* s2; short* d2; long base;
        if (r < 48)       { s2 = a.w1; d2 = a.wincat;          base = (long)r*1024; }
        else if (r < 120) { s2 = a.w3; d2 = a.wincat + 49152;  base = (long)(r-48)*1024; }
        else if (r < 132) { s2 = a.w5; d2 = a.wincat + 122880; base = (long)(r-120)*1024; }
        else if (r < 156) { s2 = a.wp; d2 = a.wincp;           base = (long)(r-132)*1024; }
        else {
            if (t < 176) a.binc[t] = (t < 64) ? a.b1[t] : (t < 160 ? a.b3[t-64] : a.b5[t-160]);
            for (int i = t; i < 2304; i += 256)
                a.bqkv[i] = (i < 768) ? a.bq[i] : (i < 1536 ? a.bk[i-768] : a.bv[i-1536]);
            for (int i = t; i < B_*D_; i += 256)
                a.pooled[i] = 0.f;
            return;
        }
        long i = base + (long)t*4;
        f32x4 v = *(const f32x4*)(s2 + i);
        d2[i+0] = f2bf(v.x); d2[i+1] = f2bf(v.y); d2[i+2] = f2bf(v.z); d2[i+3] = f2bf(v.w);
        return;
    }
    int bc = bx*32, br = by*32;
    int tx = t & 31, ty = t >> 5;
    #pragma unroll
    for (int i = 0; i < 32; i += 8)
        tile[ty + i][tx] = src[(long)(br + ty + i)*C + bc + tx];
    __syncthreads();
    #pragma unroll
    for (int i = 0; i < 32; i += 8)
        dst[(long)(bc + ty + i)*R + br + tx] = f2bf(tile[tx][ty + i]);
}

// ---------------- f32 [R,C] -> bf16 [C,R] transpose-convert (batched, opt. relu) ----------------
template<bool RELU>
__global__ void k_t2b(const float* __restrict__ in, short* __restrict__ out,
                      int R, int C, long sIn, long sOut) {
    __shared__ float tile[32][33];
    int bc = blockIdx.x * 32, br = blockIdx.y * 32;
    const float* ip = in + (long)blockIdx.z * sIn;
    short* op = out + (long)blockIdx.z * sOut;
    int tx = threadIdx.x & 31, ty = threadIdx.x >> 5;
    #pragma unroll
    for (int i = 0; i < 32; i += 8)
        tile[ty + i][tx] = ip[(long)(br + ty + i)*C + bc + tx];
    __syncthreads();
    #pragma unroll
    for (int i = 0; i < 32; i += 8) {
        float v = tile[tx][ty + i];
        if (RELU) v = fmaxf(v, 0.f);
        op[(long)(bc + ty + i)*R + br + tx] = f2bf(v);
    }
}

// ---------------- residual add + LayerNorm (f32 out optional + bf16 out) ----------------
__global__ void k_addln(const float* __restrict__ a, const float* __restrict__ bvec,
                        const float* __restrict__ g, const float* __restrict__ be,
                        float* __restrict__ outf, short* __restrict__ outb) {
    __shared__ float row[D_];
    __shared__ float red[256];
    int n = blockIdx.x, t = threadIdx.x;
    float lsum = 0.f;
    for (int d = t; d < D_; d += 256) {
        float v = a[(long)n*D_ + d] + bvec[(long)n*D_ + d];
        row[d] = v; lsum += v;
    }
    red[t] = lsum; __syncthreads();
    for (int off = 128; off > 0; off >>= 1) {
        if (t < off) red[t] += red[t+off];
        __syncthreads();
    }
    float mean = red[0] / D_; __syncthreads();
    float lvar = 0.f;
    for (int d = t; d < D_; d += 256) { float v = row[d]-mean; lvar += v*v; }
    red[t] = lvar; __syncthreads();
    for (int off = 128; off > 0; off >>= 1) {
        if (t < off) red[t] += red[t+off];
        __syncthreads();
    }
    float rstd = rsqrtf(red[0]/D_ + 1e-5f);
    for (int d = t; d < D_; d += 256) {
        float v = (row[d]-mean)*rstd*g[d] + be[d];
        if (outf) outf[(long)n*D_ + d] = v;
        outb[(long)n*D_ + d] = f2bf(v);
    }
}

// ---------------- mean-pool over sequence (parallel partials + atomics) ----------------
__global__ __launch_bounds__(256) void k_pool(const short* __restrict__ h,
                                              float* __restrict__ pooled) {
    int blk = blockIdx.x;
    int b = blk >> 4, ch = blk & 15;
    int t = threadIdx.x;
    float s0 = 0.f, s1 = 0.f, s2 = 0.f;
    for (int ss = ch*64; ss < ch*64 + 64; ss++) {
        const short* row = h + (long)(b*S_ + ss)*D_;
        s0 += b2fs(row[t]);
        s1 += b2fs(row[t + 256]);
        s2 += b2fs(row[t + 512]);
    }
    atomicAdd(&pooled[b*D_ + t],       s0 * (1.f/S_));
    atomicAdd(&pooled[b*D_ + t + 256], s1 * (1.f/S_));
    atomicAdd(&pooled[b*D_ + t + 512], s2 * (1.f/S_));
}

// ---------------- task head (parallel reduce; block per batch) ----------------
__global__ __launch_bounds__(256) void k_task(const float* __restrict__ pooled,
                                              const float* __restrict__ tw,
                                              const float* __restrict__ tb,
                                              float* __restrict__ out) {
    __shared__ float red[256][3];
    int b = blockIdx.x, t = threadIdx.x;
    float a0 = 0.f, a1 = 0.f, a2 = 0.f;
    for (int d = t; d < D_; d += 256) {
        float p = pooled[b*D_ + d];
        a0 += p*tw[d*3+0]; a1 += p*tw[d*3+1]; a2 += p*tw[d*3+2];
    }
    red[t][0] = a0; red[t][1] = a1; red[t][2] = a2;
    __syncthreads();
    for (int off = 128; off > 0; off >>= 1) {
        if (t < off) {
            red[t][0] += red[t+off][0];
            red[t][1] += red[t+off][1];
            red[t][2] += red[t+off][2];
        }
        __syncthreads();
    }
    if (t < 3) out[(long)NTOK*V_ + b*3 + t] = red[0][t] + tb[t];
}

extern "C" void kernel_launch(void* const* d_in, const int* in_sizes, int n_in,
                              void* d_out, int out_size, void* d_ws, size_t ws_size,
                              hipStream_t stream) {
    const int*   x      = (const int*)d_in[0];
    const int*   amask  = (const int*)d_in[1];
    const float* adj    = (const float*)d_in[2];
    const float* emb    = (const float*)d_in[3];
    const float* inc1_w = (const float*)d_in[4];  const float* inc1_b = (const float*)d_in[5];
    const float* inc3a_w= (const float*)d_in[6];  const float* inc3a_b= (const float*)d_in[7];
    const float* inc3b_w= (const float*)d_in[8];  const float* inc3b_b= (const float*)d_in[9];
    const float* inc5a_w= (const float*)d_in[10]; const float* inc5a_b= (const float*)d_in[11];
    const float* inc5b_w= (const float*)d_in[12]; const float* inc5b_b= (const float*)d_in[13];
    const float* incp_w = (const float*)d_in[14]; const float* incp_b = (const float*)d_in[15];
    const float* q_rot  = (const float*)d_in[16]; const float* q_ent  = (const float*)d_in[17];
    const float* gnn_w1 = (const float*)d_in[18]; const float* gnn_b1 = (const float*)d_in[19];
    const float* gnn_w2 = (const float*)d_in[20]; const float* gnn_b2 = (const float*)d_in[21];
    const float* wq = (const float*)d_in[22]; const float* bq = (const float*)d_in[23];
    const float* wk = (const float*)d_in[24]; const float* bk = (const float*)d_in[25];
    const float* wv = (const float*)d_in[26]; const float* bv = (const float*)d_in[27];
    const float* wo = (const float*)d_in[28]; const float* bo = (const float*)d_in[29];
    const float* ff_w1 = (const float*)d_in[30]; const float* ff_b1 = (const float*)d_in[31];
    const float* ff_w2 = (const float*)d_in[32]; const float* ff_b2 = (const float*)d_in[33];
    const float* ln1_g = (const float*)d_in[34]; const float* ln1_b = (const float*)d_in[35];
    const float* ln2_g = (const float*)d_in[36]; const float* ln2_b = (const float*)d_in[37];
    const float* out_w = (const float*)d_in[38]; const float* out_b = (const float*)d_in[39];
    const float* task_w= (const float*)d_in[40]; const float* task_b= (const float*)d_in[41];

    // d_out arena (f32 slot offsets; non-overlapping; dead before vocab GEMM).
    // Zero-spans contiguous: [CO..h1f) = [6636032, 8569344); [gbf..ao2) = [24363520, 28295680).
    float* F = (float*)d_out;
    short* wqkvt = (short*)(F + 0L);
    short* gw1t  = (short*)(F + 1179648L);
    short* gw2t  = (short*)(F + 1327104L);
    short* fw1t  = (short*)(F + 1474560L);
    short* fw2t  = (short*)(F + 2654208L);
    short* wincat= (short*)(F + 3833856L);
    short* wincp = (short*)(F + 3950592L);
    float* binc  = F + 4012032L;
    float* bqkv  = F + 4012288L;
    short* adjb  = (short*)(F + 4014592L);
    short* h0b   = (short*)(F + 5063168L);
    short* mpb   = (short*)(F + 5849600L);
    float* CO    = F + 6636032L;    // 360448 slots
    float* h1f   = F + 6996480L;    // 1572864 slots
    short* h1t   = (short*)(F + 8569344L);
    short* t1b   = (short*)(F + 9355776L);
    short* gt    = (short*)(F + 10928640L);
    short* t2bv  = (short*)(F + 11321856L);
    float* h2f   = F + 11715072L;
    short* h2b   = (short*)(F + 13287936L);
    short* Qh    = (short*)(F + 14074368L);   // Kh, Vt contiguous (OMODE5)
    short* Kh    = (short*)(F + 14860800L);
    short* Vt    = (short*)(F + 15647232L);   // +pad for B-OOB
    short* ctxh  = (short*)(F + 16499200L);
    float* hlnf  = F + 18858496L;
    short* hlnb  = (short*)(F + 20431360L);
    short* ff1b  = (short*)(F + 21217792L);   // ends 24363520
    float* gbf   = F + 24363520L;   // 786432 slots
    float* ao    = F + 25149952L;   // 1572864 slots
    float* ao2   = F + 26722816L;   // 1572864 slots; ends 28295680 < 65536000

    // d_ws
    char* W = (char*)d_ws;
    short* hfb    = (short*)(W + 0);
    float* pooled = (float*)(W + 3145728);
    short* owt    = (short*)(W + 3151872);

    auto gb = [](int M, int N, int Z) { return dim3((unsigned)(M/128), (unsigned)((N+127)/128), (unsigned)Z); };

    (void)hipFuncSetAttribute((const void*)k_vgemm, hipFuncAttributeMaxDynamicSharedMemorySize, 163840);

    // 0a. zero atomic targets (2 merged memsets; pooled zeroed inside k_wprep)
    (void)hipMemsetAsync(CO,  0, (size_t)(360448 + 1572864)*4, stream);
    (void)hipMemsetAsync(gbf, 0, (size_t)(786432 + 2*1572864)*4, stream);

    // 0b. ALL one-time converts/transposes/bias concats in ONE launch
    {
        WPArgs wa;
        wa.ow = out_w; wa.wq = wq; wa.wk = wk; wa.wv = wv; wa.wo = wo;
        wa.g1 = gnn_w1; wa.g2 = gnn_w2; wa.f1 = ff_w1; wa.f2 = ff_w2; wa.adj = adj;
        wa.w1 = inc1_w; wa.w3 = inc3a_w; wa.w5 = inc5a_w; wa.wp = incp_w;
        wa.b1 = inc1_b; wa.b3 = inc3a_b; wa.b5 = inc5a_b;
        wa.bq = bq; wa.bk = bk; wa.bv = bv;
        wa.owt = owt; wa.wqkvt = wqkvt; wa.gw1t = gw1t; wa.gw2t = gw2t;
        wa.fw1t = fw1t; wa.fw2t = fw2t; wa.adjb = adjb;
        wa.wincat = wincat; wa.wincp = wincp; wa.binc = binc; wa.bqkv = bqkv;
        wa.pooled = pooled;
        k_wprep<<<dim3(33693), 256, 0, stream>>>(wa);
    }

    // 1. embedding + maxpool fused (bf16, vectorized)
    k_embed2<<<dim3(NTOK), dim3(192), 0, stream>>>(x, emb, h0b, mpb);

    // 2. inception 1x1 GEMMs, split-K for occupancy
    k_bgemm<0,0,false,4><<<gb(NTOK, 176, 4), 256, 0, stream>>>(
        h0b, wincat, CO, nullptr, binc, 1.f, 176, D_, D_, D_, 176, 0, 0, 0);
    k_bgemm<0,0,false,8><<<gb(NTOK, 32, 8), 256, 0, stream>>>(
        mpb, wincp, h1f + 224, nullptr, incp_b, 1.f, 32, D_, D_, D_, NQ_, 0, 0, 0);

    // 3. fused conv3/conv5/copy/quantum x2
    k_mix<<<dim3(NTOK), dim3(256), 0, stream>>>(
        CO, inc3b_w, inc3b_b, inc5b_w, inc5b_b, q_rot, q_ent, h1f);

    // 4. GNN
    k_t2b<false><<<dim3(24,32,2), 256, 0, stream>>>(h1f, h1t, S_, NQ_, (long)S_*NQ_, (long)S_*NQ_);
    k_bgemm<0,1,false><<<gb(S_, NQ_, B_), 256, 0, stream>>>(
        adjb, h1t, t1b, nullptr, nullptr, 1.f, NQ_, S_, S_, S_, NQ_,
        (long)S_*S_, (long)NQ_*S_, (long)S_*NQ_);
    k_bgemm<0,0,false,4><<<gb(NTOK, 384, 4), 256, 0, stream>>>(
        t1b, gw1t, gbf, nullptr, gnn_b1, 1.f, 384, D_, D_, D_, 384, 0, 0, 0);
    k_t2b<true><<<dim3(12,32,2), 256, 0, stream>>>(gbf, gt, S_, 384, (long)S_*384, (long)S_*384);
    k_bgemm<0,1,false><<<gb(S_, 384, B_), 256, 0, stream>>>(
        adjb, gt, t2bv, nullptr, nullptr, 1.f, 384, S_, S_, S_, 384,
        (long)S_*S_, (long)384*S_, (long)S_*384);
    k_bgemm<0,2,false><<<gb(NTOK, D_, 1), 256, 0, stream>>>(
        t2bv, gw2t, h2b, h2f, gnn_b2, 1.f, D_, 384, 384, 384, D_, 0, 0, 0);

    // 5. attention: fused QKV -> flash attention -> WO -> add+LN
    k_bgemm<0,5,false><<<gb(NTOK, 3*D_, 1), 256, 0, stream>>>(
        h2b, wqkvt, Qh, nullptr, bqkv, 1.f, 3*D_, D_, D_, D_, 0, 0, 0, 0);
    k_fattn<<<dim3(S_/64, B_*H_), 256, 0, stream>>>(Qh, Kh, Vt, amask, ctxh);
    k_bgemm<1,0,false,2><<<gb(NTOK, D_, 2), 256, 0, stream>>>(
        ctxh, wqkvt + 3L*589824, ao, nullptr, bo, 1.f, D_, D_, D_, D_, D_, 0, 0, 0);
    k_addln<<<dim3(NTOK), dim3(256), 0, stream>>>(h2f, ao, ln1_g, ln1_b, hlnf, hlnb);

    // 6. FFN
    k_bgemm<0,1,true><<<gb(NTOK, 4*D_, 1), 256, 0, stream>>>(
        hlnb, fw1t, ff1b, nullptr, ff_b1, 1.f, 4*D_, D_, D_, D_, 4*D_, 0, 0, 0);
    k_bgemm<0,0,false,4><<<gb(NTOK, D_, 4), 256, 0, stream>>>(
        ff1b, fw2t, ao2, nullptr, ff_b2, 1.f, D_, 4*D_, 4*D_, 4*D_, D_, 0, 0, 0);
    k_addln<<<dim3(NTOK), dim3(256), 0, stream>>>(hlnf, ao2, ln2_g, ln2_b, nullptr, hfb);

    // 7. heads: parallel pool, vocab GEMM (256^2 ring-5 depth-4), parallel task
    k_pool<<<dim3(B_*16), dim3(256), 0, stream>>>(hfb, pooled);
    k_vgemm<<<dim3(NTOK/256, V_/256, 1), dim3(512), 163840, stream>>>(
        hfb, owt, (float*)d_out, out_b, V_, D_, D_, D_, V_);
    k_task<<<dim3(B_), dim3(256), 0, stream>>>(pooled, task_w, task_b, (float*)d_out);
}

// Round 20
// 632.739 us; speedup vs baseline: 1.0275x; 1.0032x over previous
//
#include <hip/hip_runtime.h>
#include <hip/hip_bf16.h>

#define B_ 2
#define S_ 1024
#define D_ 768
#define H_ 12
#define HD_ 64
#define V_ 32000
#define NQ_ 768
#define NTOK (B_*S_)
#define QKVS 1572864L   // shorts per Q/K/V segment [B,H,S,64]

typedef __attribute__((ext_vector_type(8))) short short8;
typedef __attribute__((ext_vector_type(4))) short s16x4;
typedef __attribute__((ext_vector_type(4))) float f32x4;
typedef __attribute__((ext_vector_type(4))) int i32x4;

typedef const __attribute__((address_space(1))) void* as1vp;
typedef __attribute__((address_space(3))) void* as3vp;

__device__ __forceinline__ short f2bf(float f) {
    union { float f; unsigned u; } v; v.f = f;
    unsigned r = (v.u + 0x7FFFu + ((v.u >> 16) & 1u)) >> 16;
    return (short)r;
}
__device__ __forceinline__ float b2fs(short s) {
    union { unsigned u; float f; } v; v.u = ((unsigned)(unsigned short)s) << 16;
    return v.f;
}

// ---------------- embedding + maxpool3 fused (vectorized f32x4 / s16x4) ----------------
__global__ __launch_bounds__(192) void k_embed2(
    const int* __restrict__ x, const float* __restrict__ emb,
    short* __restrict__ h0b, short* __restrict__ mpb) {
    int n = blockIdx.x; int s = n & (S_-1);
    int r0 = x[n];
    int rm = (s > 0)      ? x[n-1] : -1;
    int rp = (s < S_-1)   ? x[n+1] : -1;
    int d = threadIdx.x * 4;   // 192 threads x 4 = 768
    f32x4 e = *(const f32x4*)(emb + (long)r0*D_ + d);
    f32x4 m = e;
    if (rm >= 0) {
        f32x4 a = *(const f32x4*)(emb + (long)rm*D_ + d);
        #pragma unroll
        for (int j = 0; j < 4; j++) m[j] = fmaxf(m[j], a[j]);
    }
    if (rp >= 0) {
        f32x4 a = *(const f32x4*)(emb + (long)rp*D_ + d);
        #pragma unroll
        for (int j = 0; j < 4; j++) m[j] = fmaxf(m[j], a[j]);
    }
    s16x4 ev, mv;
    #pragma unroll
    for (int j = 0; j < 4; j++) { ev[j] = f2bf(e[j]); mv[j] = f2bf(m[j]); }
    *(s16x4*)(h0b + (long)n*D_ + d) = ev;
    *(s16x4*)(mpb + (long)n*D_ + d) = mv;
}

// ---------------- fused conv3+conv5+copy+incp-merge+quantum x2 ----------------
__global__ __launch_bounds__(256) void k_mix(
    const float* __restrict__ CO, const float* __restrict__ c3w,
    const float* __restrict__ c3b, const float* __restrict__ c5w,
    const float* __restrict__ c5b, const float* __restrict__ q_rot,
    const float* __restrict__ q_ent, float* __restrict__ h1f)
{
    __shared__ float co[5][176];
    __shared__ float ta[NQ_];
    __shared__ float tb[NQ_];
    int n = blockIdx.x; int s = n & (S_-1);
    int t = threadIdx.x;
    for (int idx = t; idx < 5*176; idx += 256) {
        int dr = idx / 176 - 2, c = idx % 176;
        int ss = s + dr;
        co[idx/176][c] = (ss >= 0 && ss < S_) ? CO[(long)(n + dr)*176 + c] : 0.f;
    }
    for (int d = 256 + t; d < NQ_; d += 256) ta[d] = 0.f;
    __syncthreads();
    if (t < 64) {
        ta[t] = co[2][t];
    } else if (t < 192) {
        int o = t - 64;
        float acc = c3b[o];
        #pragma unroll
        for (int k = 0; k < 3; k++)
            for (int i = 0; i < 96; i++)
                acc += co[1+k][64+i] * c3w[(o*96+i)*3 + k];
        ta[t] = acc;
    } else if (t < 224) {
        int o = t - 192;
        float acc = c5b[o];
        #pragma unroll
        for (int k = 0; k < 5; k++)
            for (int i = 0; i < 16; i++)
                acc += co[k][160+i] * c5w[(o*16+i)*5 + k];
        ta[t] = acc;
    } else {
        ta[t] = h1f[(long)n*NQ_ + t];
    }
    __syncthreads();
    #pragma unroll
    for (int layer = 0; layer < 2; layer++) {
        const float* rot = q_rot + (long)layer*NQ_*3;
        const float* ent = q_ent + (long)layer*(NQ_-1);
        for (int q = t; q < NQ_; q += 256) {
            float hv = ta[q];
            tb[q] = __sinf(hv + rot[q*3]) + __sinf(hv + rot[q*3+1]) + __sinf(hv + rot[q*3+2]);
        }
        __syncthreads();
        for (int q = t; q < NQ_; q += 256) {
            float v;
            if (q == NQ_-1) v = 0.f;
            else {
                int qm = (q == 0) ? (NQ_-1) : (q-1);
                v = tb[q]*__sinf(ent[q]) + tb[qm]*__cosf(ent[q]);
            }
            ta[q] = v;
        }
        __syncthreads();
    }
    for (int q = t; q < NQ_; q += 256) h1f[(long)n*NQ_ + q] = ta[q];
}

// ---------------- bf16 MFMA GEMM (128x128, 2-phase, optional split-K) ----------------
template<int AMODE, int OMODE, bool RELU, int KSPLIT = 1>
__global__ __launch_bounds__(256) void k_bgemm(
    const short* __restrict__ A, const short* __restrict__ Bm,
    void* __restrict__ Cv, float* __restrict__ C2,
    const float* __restrict__ bias, float scale,
    int N, int K, int lda, int ldb, int ldc,
    long sA, long sB, long sC)
{
    __shared__ short lds[2][8192];
    const int t = threadIdx.x;
    const int lane = t & 63, wave = t >> 6;
    const int wm = wave >> 1, wn = wave & 1;
    const int l15 = lane & 15, l4 = lane >> 4;

    int bx = blockIdx.x, by = blockIdx.y;
    if (KSPLIT == 1 && gridDim.z == 1) {
        int lin = by * gridDim.x + bx;
        int nwg = gridDim.x * gridDim.y;
        int xcd = lin & 7, pos = lin >> 3;
        int q = nwg >> 3, r = nwg & 7;
        int lin2 = (xcd < r ? xcd*(q+1) : r*(q+1) + (xcd-r)*q) + pos;
        bx = lin2 % gridDim.x;
        by = lin2 / gridDim.x;
    }
    const int tile_m = bx * 128, tile_n = by * 128;
    const int kz = (KSPLIT > 1) ? blockIdx.z : 0;
    const int Keff = K / KSPLIT;
    const int kbase = kz * Keff;
    const long aoff = (KSPLIT > 1) ? 0 : (long)blockIdx.z * sA;
    const long boff = (KSPLIT > 1) ? 0 : (long)blockIdx.z * sB;
    const long coff = (KSPLIT > 1) ? 0 : (long)blockIdx.z * sC;

    const int cA0 = t, cA1 = t + 256;
    const int arow0 = tile_m + ((cA0 >> 6) << 4) + (cA0 & 15);
    const int arow1 = tile_m + ((cA1 >> 6) << 4) + (cA1 & 15);
    const int akb0 = ((cA0 >> 4) & 3) * 8;
    const int akb1 = ((cA1 >> 4) & 3) * 8;
    const int bcol0 = tile_n + (((cA0 >> 4) & 7) << 4) + (cA0 & 15);
    const int bcol1 = tile_n + (((cA1 >> 4) & 7) << 4) + (cA1 & 15);
    const int bkb0 = (cA0 >> 7) * 8;
    const int bkb1 = (cA1 >> 7) * 8;
    const short* bp0 = Bm + boff + (long)bcol0*ldb + bkb0 + kbase;
    const short* bp1 = Bm + boff + (long)bcol1*ldb + bkb1 + kbase;
    const short* ap0 = nullptr; const short* ap1 = nullptr;
    long abase0 = 0, abase1 = 0;
    if (AMODE == 0) {
        ap0 = A + aoff + (long)arow0*lda + akb0 + kbase;
        ap1 = A + aoff + (long)arow1*lda + akb1 + kbase;
    } else {
        abase0 = ((long)((arow0 >> 10)*H_) * S_ + (arow0 & (S_-1))) * 64;
        abase1 = ((long)((arow1 >> 10)*H_) * S_ + (arow1 & (S_-1))) * 64;
    }
    const int wb = wave * 1024;

    auto stage = [&](int buf, int k0) {
        char* lb = (char*)&lds[buf][0];
        const short *a0, *a1;
        if (AMODE == 0) { a0 = ap0 + k0; a1 = ap1 + k0; }
        else {
            int ka0 = kbase + k0 + akb0, ka1 = kbase + k0 + akb1;
            a0 = A + abase0 + (long)(ka0 >> 6)*(S_*64) + (ka0 & 63);
            a1 = A + abase1 + (long)(ka1 >> 6)*(S_*64) + (ka1 & 63);
        }
        __builtin_amdgcn_global_load_lds((as1vp)a0,          (as3vp)(lb + wb),          16, 0, 0);
        __builtin_amdgcn_global_load_lds((as1vp)a1,          (as3vp)(lb + 4096 + wb),   16, 0, 0);
        __builtin_amdgcn_global_load_lds((as1vp)(bp0 + k0),  (as3vp)(lb + 8192 + wb),   16, 0, 0);
        __builtin_amdgcn_global_load_lds((as1vp)(bp1 + k0),  (as3vp)(lb + 12288 + wb),  16, 0, 0);
    };

    f32x4 acc[4][4] = {};
    const int nk = Keff >> 5;
    stage(0, 0);
    __syncthreads();
    int cur = 0;
    for (int ks = 0; ks < nk; ks++) {
        if (ks + 1 < nk) stage(cur ^ 1, (ks + 1) << 5);
        short8 af[4], bfv[4];
        const short* lb = &lds[cur][0];
        #pragma unroll
        for (int m = 0; m < 4; m++)
            af[m] = *(const short8*)(lb + (wm*4 + m)*512 + l4*128 + l15*8);
        #pragma unroll
        for (int n = 0; n < 4; n++)
            bfv[n] = *(const short8*)(lb + 4096 + l4*1024 + (wn*4 + n)*128 + l15*8);
        #pragma unroll
        for (int m = 0; m < 4; m++)
            #pragma unroll
            for (int n = 0; n < 4; n++)
                acc[m][n] = __builtin_amdgcn_mfma_f32_16x16x32_bf16(af[m], bfv[n], acc[m][n], 0, 0, 0);
        __syncthreads();
        cur ^= 1;
    }

    #pragma unroll
    for (int m = 0; m < 4; m++) {
        #pragma unroll
        for (int n = 0; n < 4; n++) {
            int col = tile_n + wn*64 + n*16 + l15;
            if (col >= N) continue;
            float bv = (bias && (KSPLIT == 1 || kz == 0)) ? bias[col] : 0.f;
            #pragma unroll
            for (int r = 0; r < 4; r++) {
                int row = tile_m + wm*64 + m*16 + l4*4 + r;
                float v = acc[m][n][r] * scale + bv;
                if (RELU) v = fmaxf(v, 0.f);
                if (OMODE == 0) {
                    if (KSPLIT > 1)
                        atomicAdd(&((float*)Cv)[(long)row*ldc + col], v);
                    else
                        ((float*)Cv)[coff + (long)row*ldc + col] = v;
                } else if (OMODE == 1) {
                    ((short*)Cv)[coff + (long)row*ldc + col] = f2bf(v);
                } else if (OMODE == 2) {
                    C2[coff + (long)row*ldc + col] = v;
                    ((short*)Cv)[coff + (long)row*ldc + col] = f2bf(v);
                } else {   // OMODE 5: fused QKV routing
                    int seg = (col >= 1536) ? 2 : ((col >= 768) ? 1 : 0);
                    int c = col - seg*768;
                    int hh = c >> 6, dd = c & 63;
                    int b = row >> 10, s = row & (S_-1);
                    long hidx = (long)(b*H_ + hh);
                    short* base = (short*)Cv;
                    if (seg < 2) base[(long)seg*QKVS + (hidx*S_ + s)*64 + dd] = f2bf(v);
                    else         base[2L*QKVS + (hidx*64 + dd)*S_ + s] = f2bf(v);
                }
            }
        }
    }
}

// ---------------- 256x256 ring-5 depth-3 counted-vmcnt MFMA GEMM (vocab; measured best) ----------------
// Structural plateau: 610 TF here = m233's 2-phase ceiling (607 TF). Schedule space
// exhausted by A/B: ring{2,3,5} x depth{1..4} x BK{32,64} x tile{128^2,256x128,256^2}
// all land 165-202us. Escape = full m201 8-phase co-designed stagger (not attempted blind).
__global__ __launch_bounds__(512, 1) void k_vgemm(
    const short* __restrict__ A, const short* __restrict__ Bm,
    float* __restrict__ C, const float* __restrict__ bias,
    int N, int K, int lda, int ldb, int ldc)
{
    extern __shared__ short lds[];   // 81920 shorts = 160 KiB
    const int t = threadIdx.x;
    const int lane = t & 63, wave = t >> 6;
    const int wm = wave >> 2, wn = wave & 3;
    const int l15 = lane & 15, l4 = lane >> 4;
    int bx = blockIdx.x, by = blockIdx.y;
    {   // XCD-chunked bijective swizzle
        int lin = by * gridDim.x + bx;
        int nwg = gridDim.x * gridDim.y;
        int xcd = lin & 7, pos = lin >> 3;
        int q = nwg >> 3, r = nwg & 7;
        int lin2 = (xcd < r ? xcd*(q+1) : r*(q+1) + (xcd-r)*q) + pos;
        bx = lin2 % gridDim.x; by = lin2 / gridDim.x;
    }
    const int tile_m = bx * 256, tile_n = by * 256;

    const int c0 = wave*128 + lane;
    const int c1 = c0 + 64;
    const int ar0 = ((c0 >> 6) << 4) + (c0 & 15), ak0 = ((c0 >> 4) & 3) << 3;
    const int ar1 = ((c1 >> 6) << 4) + (c1 & 15), ak1 = ((c1 >> 4) & 3) << 3;
    const short* pa0 = A + (long)(tile_m + ar0)*lda + ak0;
    const short* pa1 = A + (long)(tile_m + ar1)*lda + ak1;
    const short* pb0 = Bm + (long)(tile_n + ar0)*ldb + ak0;
    const short* pb1 = Bm + (long)(tile_n + ar1)*ldb + ak1;
    char* lb = (char*)lds;
    const int wb0 = wave*2048, wb1 = wave*2048 + 1024;

    auto stage = [&](int reg, int s) {
        int k = s << 5;
        char* ab = lb + reg*32768;
        __builtin_amdgcn_global_load_lds((as1vp)(pa0 + k), (as3vp)(ab + wb0),         16, 0, 0);
        __builtin_amdgcn_global_load_lds((as1vp)(pa1 + k), (as3vp)(ab + wb1),         16, 0, 0);
        __builtin_amdgcn_global_load_lds((as1vp)(pb0 + k), (as3vp)(ab + 16384 + wb0), 16, 0, 0);
        __builtin_amdgcn_global_load_lds((as1vp)(pb1 + k), (as3vp)(ab + 16384 + wb1), 16, 0, 0);
    };

    f32x4 acc[8][4] = {};
    const int nks = K >> 5;
    stage(0, 0); stage(1, 1); stage(2, 2);
    const int ard = ((wm*8) << 10) + (l4 << 8) + l15*16;
    const int brd = 16384 + ((wn*4) << 10) + (l4 << 8) + l15*16;

    int reg = 0;
    for (int s = 0; s < nks; s++) {
        if (s + 3 < nks) {
            int r3 = reg + 3; if (r3 >= 5) r3 -= 5;
            stage(r3, s + 3);
        }
        if (s < nks - 3)       asm volatile("s_waitcnt vmcnt(12)" ::: "memory");
        else if (s == nks - 3) asm volatile("s_waitcnt vmcnt(8)"  ::: "memory");
        else if (s == nks - 2) asm volatile("s_waitcnt vmcnt(4)"  ::: "memory");
        else                   asm volatile("s_waitcnt vmcnt(0)"  ::: "memory");
        __builtin_amdgcn_s_barrier();
        const char* rb = lb + reg*32768;
        short8 a[8], b[4];
        #pragma unroll
        for (int fr = 0; fr < 8; fr++) a[fr] = *(const short8*)(rb + ard + (fr << 10));
        #pragma unroll
        for (int fc = 0; fc < 4; fc++) b[fc] = *(const short8*)(rb + brd + (fc << 10));
        __builtin_amdgcn_s_setprio(1);
        #pragma unroll
        for (int fr = 0; fr < 8; fr++)
            #pragma unroll
            for (int fc = 0; fc < 4; fc++)
                acc[fr][fc] = __builtin_amdgcn_mfma_f32_16x16x32_bf16(a[fr], b[fc], acc[fr][fc], 0, 0, 0);
        __builtin_amdgcn_s_setprio(0);
        if (++reg == 5) reg = 0;
    }

    #pragma unroll
    for (int fr = 0; fr < 8; fr++) {
        #pragma unroll
        for (int fc = 0; fc < 4; fc++) {
            int col = tile_n + wn*64 + fc*16 + l15;
            float bv = bias ? bias[col] : 0.f;
            #pragma unroll
            for (int rr = 0; rr < 4; rr++) {
                int row = tile_m + wm*128 + fr*16 + l4*4 + rr;
                C[(long)row*ldc + col] = acc[fr][fc][rr] + bv;
            }
        }
    }
}

// ---------------- flash attention: QK^T/8 + mask-bug + online softmax + PV ----------------
__global__ __launch_bounds__(256) void k_fattn(
    const short* __restrict__ Q, const short* __restrict__ K,
    const short* __restrict__ Vt, const int* __restrict__ mask,
    short* __restrict__ ctx)
{
    __shared__ short plds[4096];   // 4 waves x [16 q][64 kv]
    const int t = threadIdx.x;
    const int lane = t & 63, wave = t >> 6;
    const int l15 = lane & 15, l4 = lane >> 4;
    const int qt = blockIdx.x, z = blockIdx.y;
    const int b = z / H_;
    const long zb = (long)z * S_ * 64;

    const int q = qt*64 + wave*16 + l15;
    short8 aq0 = *(const short8*)(Q + zb + (long)q*64 + l4*8);
    short8 aq1 = *(const short8*)(Q + zb + (long)q*64 + l4*8 + 32);

    float m[4] = {-1e30f, -1e30f, -1e30f, -1e30f};
    float l[4] = {0.f, 0.f, 0.f, 0.f};
    f32x4 O[4] = {};
    short* pw = plds + wave*1024;

    for (int kt = 0; kt < 16; kt++) {
        const int kvb = kt*64;
        f32x4 s[4] = {};
        #pragma unroll
        for (int ct = 0; ct < 4; ct++) {
            const short* kp = K + zb + (long)(kvb + ct*16 + l15)*64 + l4*8;
            short8 b0 = *(const short8*)(kp);
            short8 b1 = *(const short8*)(kp + 32);
            s[ct] = __builtin_amdgcn_mfma_f32_16x16x32_bf16(aq0, b0, s[ct], 0, 0, 0);
            s[ct] = __builtin_amdgcn_mfma_f32_16x16x32_bf16(aq1, b1, s[ct], 0, 0, 0);
        }
        float p[4][4];
        float rmax[4] = {-1e30f, -1e30f, -1e30f, -1e30f};
        #pragma unroll
        for (int ct = 0; ct < 4; ct++) {
            int mv = mask[b*S_ + kvb + ct*16 + l15];
            #pragma unroll
            for (int r = 0; r < 4; r++) {
                float v = (mv == 1) ? -1e9f : s[ct][r]*0.125f;
                p[ct][r] = v;
                rmax[r] = fmaxf(rmax[r], v);
            }
        }
        #pragma unroll
        for (int r = 0; r < 4; r++) {
            float v = rmax[r];
            v = fmaxf(v, __shfl_xor(v, 1));
            v = fmaxf(v, __shfl_xor(v, 2));
            v = fmaxf(v, __shfl_xor(v, 4));
            v = fmaxf(v, __shfl_xor(v, 8));
            float mn = fmaxf(m[r], v);
            float corr = __expf(m[r] - mn);
            float srow = 0.f;
            #pragma unroll
            for (int ct = 0; ct < 4; ct++) {
                float e = __expf(p[ct][r] - mn);
                p[ct][r] = e;
                srow += e;
            }
            srow += __shfl_xor(srow, 1);
            srow += __shfl_xor(srow, 2);
            srow += __shfl_xor(srow, 4);
            srow += __shfl_xor(srow, 8);
            l[r] = l[r]*corr + srow;
            m[r] = mn;
            #pragma unroll
            for (int c2 = 0; c2 < 4; c2++) O[c2][r] *= corr;
        }
        #pragma unroll
        for (int ct = 0; ct < 4; ct++)
            #pragma unroll
            for (int r = 0; r < 4; r++)
                pw[(l4*4 + r)*64 + ct*16 + l15] = f2bf(p[ct][r]);
        asm volatile("s_waitcnt lgkmcnt(0)" ::: "memory");
        __builtin_amdgcn_sched_barrier(0);
        short8 pa0 = *(const short8*)(pw + l15*64 + l4*8);
        short8 pa1 = *(const short8*)(pw + l15*64 + l4*8 + 32);
        #pragma unroll
        for (int c2 = 0; c2 < 4; c2++) {
            const short* vp = Vt + zb + (long)(c2*16 + l15)*S_ + kvb + l4*8;
            short8 v0 = *(const short8*)(vp);
            short8 v1 = *(const short8*)(vp + 32);
            O[c2] = __builtin_amdgcn_mfma_f32_16x16x32_bf16(pa0, v0, O[c2], 0, 0, 0);
            O[c2] = __builtin_amdgcn_mfma_f32_16x16x32_bf16(pa1, v1, O[c2], 0, 0, 0);
        }
    }
    #pragma unroll
    for (int r = 0; r < 4; r++) {
        float inv = 1.f / l[r];
        int qo = qt*64 + wave*16 + l4*4 + r;
        #pragma unroll
        for (int c2 = 0; c2 < 4; c2++)
            ctx[zb + (long)qo*64 + c2*16 + l15] = f2bf(O[c2][r] * inv);
    }
}

// ---------------- mega prep: ALL weight transposes/converts/biases in one launch ----------------
struct WPArgs {
    const float *ow, *wq, *wk, *wv, *wo, *g1, *g2, *f1, *f2, *adj;
    const float *w1, *w3, *w5, *wp, *b1, *b3, *b5, *bq, *bk, *bv;
    short *owt, *wqkvt, *gw1t, *gw2t, *fw1t, *fw2t, *adjb, *wincat, *wincp;
    float *binc, *bqkv, *pooled;
};
__global__ __launch_bounds__(256) void k_wprep(WPArgs a) {
    __shared__ float tile[32][33];
    int blk = blockIdx.x, t = threadIdx.x;
    const float* src; short* dst;
    int R, C, bx, by;
    if (blk < 24000)      { src = a.ow; dst = a.owt; R = 768; C = 32000; bx = blk % 1000; by = blk / 1000; }
    else if (blk < 26304) { int r = blk - 24000; int z = r / 576; r %= 576;
        src = (z == 0) ? a.wq : (z == 1) ? a.wk : (z == 2) ? a.wv : a.wo;
        dst = a.wqkvt + (long)z*589824; R = 768; C = 768; bx = r % 24; by = r / 24; }
    else if (blk < 26592) { int r = blk - 26304; src = a.g1; dst = a.gw1t; R = 768; C = 384;  bx = r % 12; by = r / 12; }
    else if (blk < 26880) { int r = blk - 26592; src = a.g2; dst = a.gw2t; R = 384; C = 768;  bx = r % 24; by = r / 24; }
    else if (blk < 29184) { int r = blk - 26880; src = a.f1; dst = a.fw1t; R = 768; C = 3072; bx = r % 96; by = r / 96; }
    else if (blk < 31488) { int r = blk - 29184; src = a.f2; dst = a.fw2t; R = 3072; C = 768; bx = r % 24; by = r / 24; }
    else if (blk < 33536) {
        long i = ((long)(blk - 31488)*256 + t)*4;
        f32x4 v = *(const f32x4*)(a.adj + i);
        a.adjb[i+0] = f2bf(v.x); a.adjb[i+1] = f2bf(v.y);
        a.adjb[i+2] = f2bf(v.z); a.adjb[i+3] = f2bf(v.w);
        return;
    } else {
        int r = blk - 33536;
        const float* s2; short* d2; long base;
        if (r < 48)       { s2 = a.w1; d2 = a.wincat;          base = (long)r*1024; }
        else if (r < 120) { s2 = a.w3; d2 = a.wincat + 49152;  base = (long)(r-48)*1024; }
        else if (r < 132) { s2 = a.w5; d2 = a.wincat + 122880; base = (long)(r-120)*1024; }
        else if (r < 156) { s2 = a.wp; d2 = a.wincp;           base = (long)(r-132)*1024; }
        else {
            if (t < 176) a.binc[t] = (t < 64) ? a.b1[t] : (t < 160 ? a.b3[t-64] : a.b5[t-160]);
            for (int i = t; i < 2304; i += 256)
                a.bqkv[i] = (i < 768) ? a.bq[i] : (i < 1536 ? a.bk[i-768] : a.bv[i-1536]);
            for (int i = t; i < B_*D_; i += 256)
                a.pooled[i] = 0.f;
            return;
        }
        long i = base + (long)t*4;
        f32x4 v = *(const f32x4*)(s2 + i);
        d2[i+0] = f2bf(v.x); d2[i+1] = f2bf(v.y); d2[i+2] = f2bf(v.z); d2[i+3] = f2bf(v.w);
        return;
    }
    int bc = bx*32, br = by*32;
    int tx = t & 31, ty = t >> 5;
    #pragma unroll
    for (int i = 0; i < 32; i += 8)
        tile[ty + i][tx] = src[(long)(br + ty + i)*C + bc + tx];
    __syncthreads();
    #pragma unroll
    for (int i = 0; i < 32; i += 8)
        dst[(long)(bc + ty + i)*R + br + tx] = f2bf(tile[tx][ty + i]);
}

// ---------------- f32 [R,C] -> bf16 [C,R] transpose-convert (batched, opt. relu) ----------------
template<bool RELU>
__global__ void k_t2b(const float* __restrict__ in, short* __restrict__ out,
                      int R, int C, long sIn, long sOut) {
    __shared__ float tile[32][33];
    int bc = blockIdx.x * 32, br = blockIdx.y * 32;
    const float* ip = in + (long)blockIdx.z * sIn;
    short* op = out + (long)blockIdx.z * sOut;
    int tx = threadIdx.x & 31, ty = threadIdx.x >> 5;
    #pragma unroll
    for (int i = 0; i < 32; i += 8)
        tile[ty + i][tx] = ip[(long)(br + ty + i)*C + bc + tx];
    __syncthreads();
    #pragma unroll
    for (int i = 0; i < 32; i += 8) {
        float v = tile[tx][ty + i];
        if (RELU) v = fmaxf(v, 0.f);
        op[(long)(bc + ty + i)*R + br + tx] = f2bf(v);
    }
}

// ---------------- residual add + LayerNorm (f32 out optional + bf16 out) ----------------
__global__ void k_addln(const float* __restrict__ a, const float* __restrict__ bvec,
                        const float* __restrict__ g, const float* __restrict__ be,
                        float* __restrict__ outf, short* __restrict__ outb) {
    __shared__ float row[D_];
    __shared__ float red[256];
    int n = blockIdx.x, t = threadIdx.x;
    float lsum = 0.f;
    for (int d = t; d < D_; d += 256) {
        float v = a[(long)n*D_ + d] + bvec[(long)n*D_ + d];
        row[d] = v; lsum += v;
    }
    red[t] = lsum; __syncthreads();
    for (int off = 128; off > 0; off >>= 1) {
        if (t < off) red[t] += red[t+off];
        __syncthreads();
    }
    float mean = red[0] / D_; __syncthreads();
    float lvar = 0.f;
    for (int d = t; d < D_; d += 256) { float v = row[d]-mean; lvar += v*v; }
    red[t] = lvar; __syncthreads();
    for (int off = 128; off > 0; off >>= 1) {
        if (t < off) red[t] += red[t+off];
        __syncthreads();
    }
    float rstd = rsqrtf(red[0]/D_ + 1e-5f);
    for (int d = t; d < D_; d += 256) {
        float v = (row[d]-mean)*rstd*g[d] + be[d];
        if (outf) outf[(long)n*D_ + d] = v;
        outb[(long)n*D_ + d] = f2bf(v);
    }
}

// ---------------- mean-pool over sequence (parallel partials + atomics) ----------------
__global__ __launch_bounds__(256) void k_pool(const short* __restrict__ h,
                                              float* __restrict__ pooled) {
    int blk = blockIdx.x;
    int b = blk >> 4, ch = blk & 15;
    int t = threadIdx.x;
    float s0 = 0.f, s1 = 0.f, s2 = 0.f;
    for (int ss = ch*64; ss < ch*64 + 64; ss++) {
        const short* row = h + (long)(b*S_ + ss)*D_;
        s0 += b2fs(row[t]);
        s1 += b2fs(row[t + 256]);
        s2 += b2fs(row[t + 512]);
    }
    atomicAdd(&pooled[b*D_ + t],       s0 * (1.f/S_));
    atomicAdd(&pooled[b*D_ + t + 256], s1 * (1.f/S_));
    atomicAdd(&pooled[b*D_ + t + 512], s2 * (1.f/S_));
}

// ---------------- task head (parallel reduce; block per batch) ----------------
__global__ __launch_bounds__(256) void k_task(const float* __restrict__ pooled,
                                              const float* __restrict__ tw,
                                              const float* __restrict__ tb,
                                              float* __restrict__ out) {
    __shared__ float red[256][3];
    int b = blockIdx.x, t = threadIdx.x;
    float a0 = 0.f, a1 = 0.f, a2 = 0.f;
    for (int d = t; d < D_; d += 256) {
        float p = pooled[b*D_ + d];
        a0 += p*tw[d*3+0]; a1 += p*tw[d*3+1]; a2 += p*tw[d*3+2];
    }
    red[t][0] = a0; red[t][1] = a1; red[t][2] = a2;
    __syncthreads();
    for (int off = 128; off > 0; off >>= 1) {
        if (t < off) {
            red[t][0] += red[t+off][0];
            red[t][1] += red[t+off][1];
            red[t][2] += red[t+off][2];
        }
        __syncthreads();
    }
    if (t < 3) out[(long)NTOK*V_ + b*3 + t] = red[0][t] + tb[t];
}

extern "C" void kernel_launch(void* const* d_in, const int* in_sizes, int n_in,
                              void* d_out, int out_size, void* d_ws, size_t ws_size,
                              hipStream_t stream) {
    const int*   x      = (const int*)d_in[0];
    const int*   amask  = (const int*)d_in[1];
    const float* adj    = (const float*)d_in[2];
    const float* emb    = (const float*)d_in[3];
    const float* inc1_w = (const float*)d_in[4];  const float* inc1_b = (const float*)d_in[5];
    const float* inc3a_w= (const float*)d_in[6];  const float* inc3a_b= (const float*)d_in[7];
    const float* inc3b_w= (const float*)d_in[8];  const float* inc3b_b= (const float*)d_in[9];
    const float* inc5a_w= (const float*)d_in[10]; const float* inc5a_b= (const float*)d_in[11];
    const float* inc5b_w= (const float*)d_in[12]; const float* inc5b_b= (const float*)d_in[13];
    const float* incp_w = (const float*)d_in[14]; const float* incp_b = (const float*)d_in[15];
    const float* q_rot  = (const float*)d_in[16]; const float* q_ent  = (const float*)d_in[17];
    const float* gnn_w1 = (const float*)d_in[18]; const float* gnn_b1 = (const float*)d_in[19];
    const float* gnn_w2 = (const float*)d_in[20]; const float* gnn_b2 = (const float*)d_in[21];
    const float* wq = (const float*)d_in[22]; const float* bq = (const float*)d_in[23];
    const float* wk = (const float*)d_in[24]; const float* bk = (const float*)d_in[25];
    const float* wv = (const float*)d_in[26]; const float* bv = (const float*)d_in[27];
    const float* wo = (const float*)d_in[28]; const float* bo = (const float*)d_in[29];
    const float* ff_w1 = (const float*)d_in[30]; const float* ff_b1 = (const float*)d_in[31];
    const float* ff_w2 = (const float*)d_in[32]; const float* ff_b2 = (const float*)d_in[33];
    const float* ln1_g = (const float*)d_in[34]; const float* ln1_b = (const float*)d_in[35];
    const float* ln2_g = (const float*)d_in[36]; const float* ln2_b = (const float*)d_in[37];
    const float* out_w = (const float*)d_in[38]; const float* out_b = (const float*)d_in[39];
    const float* task_w= (const float*)d_in[40]; const float* task_b= (const float*)d_in[41];

    // d_out arena (f32 slot offsets; non-overlapping; dead before vocab GEMM).
    // Zero-spans contiguous: [CO..h1f) = [6636032, 8569344); [gbf..ao2) = [24363520, 28295680).
    float* F = (float*)d_out;
    short* wqkvt = (short*)(F + 0L);
    short* gw1t  = (short*)(F + 1179648L);
    short* gw2t  = (short*)(F + 1327104L);
    short* fw1t  = (short*)(F + 1474560L);
    short* fw2t  = (short*)(F + 2654208L);
    short* wincat= (short*)(F + 3833856L);
    short* wincp = (short*)(F + 3950592L);
    float* binc  = F + 4012032L;
    float* bqkv  = F + 4012288L;
    short* adjb  = (short*)(F + 4014592L);
    short* h0b   = (short*)(F + 5063168L);
    short* mpb   = (short*)(F + 5849600L);
    float* CO    = F + 6636032L;    // 360448 slots
    float* h1f   = F + 6996480L;    // 1572864 slots
    short* h1t   = (short*)(F + 8569344L);
    short* t1b   = (short*)(F + 9355776L);
    short* gt    = (short*)(F + 10928640L);
    short* t2bv  = (short*)(F + 11321856L);
    float* h2f   = F + 11715072L;
    short* h2b   = (short*)(F + 13287936L);
    short* Qh    = (short*)(F + 14074368L);   // Kh, Vt contiguous (OMODE5)
    short* Kh    = (short*)(F + 14860800L);
    short* Vt    = (short*)(F + 15647232L);   // +pad for B-OOB
    short* ctxh  = (short*)(F + 16499200L);
    float* hlnf  = F + 18858496L;
    short* hlnb  = (short*)(F + 20431360L);
    short* ff1b  = (short*)(F + 21217792L);   // ends 24363520
    float* gbf   = F + 24363520L;   // 786432 slots
    float* ao    = F + 25149952L;   // 1572864 slots
    float* ao2   = F + 26722816L;   // 1572864 slots; ends 28295680 < 65536000

    // d_ws
    char* W = (char*)d_ws;
    short* hfb    = (short*)(W + 0);
    float* pooled = (float*)(W + 3145728);
    short* owt    = (short*)(W + 3151872);

    auto gb = [](int M, int N, int Z) { return dim3((unsigned)(M/128), (unsigned)((N+127)/128), (unsigned)Z); };

    (void)hipFuncSetAttribute((const void*)k_vgemm, hipFuncAttributeMaxDynamicSharedMemorySize, 163840);

    // 0a. zero atomic targets (2 merged memsets; pooled zeroed inside k_wprep)
    (void)hipMemsetAsync(CO,  0, (size_t)(360448 + 1572864)*4, stream);
    (void)hipMemsetAsync(gbf, 0, (size_t)(786432 + 2*1572864)*4, stream);

    // 0b. ALL one-time converts/transposes/bias concats in ONE launch
    {
        WPArgs wa;
        wa.ow = out_w; wa.wq = wq; wa.wk = wk; wa.wv = wv; wa.wo = wo;
        wa.g1 = gnn_w1; wa.g2 = gnn_w2; wa.f1 = ff_w1; wa.f2 = ff_w2; wa.adj = adj;
        wa.w1 = inc1_w; wa.w3 = inc3a_w; wa.w5 = inc5a_w; wa.wp = incp_w;
        wa.b1 = inc1_b; wa.b3 = inc3a_b; wa.b5 = inc5a_b;
        wa.bq = bq; wa.bk = bk; wa.bv = bv;
        wa.owt = owt; wa.wqkvt = wqkvt; wa.gw1t = gw1t; wa.gw2t = gw2t;
        wa.fw1t = fw1t; wa.fw2t = fw2t; wa.adjb = adjb;
        wa.wincat = wincat; wa.wincp = wincp; wa.binc = binc; wa.bqkv = bqkv;
        wa.pooled = pooled;
        k_wprep<<<dim3(33693), 256, 0, stream>>>(wa);
    }

    // 1. embedding + maxpool fused (bf16, vectorized)
    k_embed2<<<dim3(NTOK), dim3(192), 0, stream>>>(x, emb, h0b, mpb);

    // 2. inception 1x1 GEMMs, split-K for occupancy
    k_bgemm<0,0,false,4><<<gb(NTOK, 176, 4), 256, 0, stream>>>(
        h0b, wincat, CO, nullptr, binc, 1.f, 176, D_, D_, D_, 176, 0, 0, 0);
    k_bgemm<0,0,false,8><<<gb(NTOK, 32, 8), 256, 0, stream>>>(
        mpb, wincp, h1f + 224, nullptr, incp_b, 1.f, 32, D_, D_, D_, NQ_, 0, 0, 0);

    // 3. fused conv3/conv5/copy/quantum x2
    k_mix<<<dim3(NTOK), dim3(256), 0, stream>>>(
        CO, inc3b_w, inc3b_b, inc5b_w, inc5b_b, q_rot, q_ent, h1f);

    // 4. GNN
    k_t2b<false><<<dim3(24,32,2), 256, 0, stream>>>(h1f, h1t, S_, NQ_, (long)S_*NQ_, (long)S_*NQ_);
    k_bgemm<0,1,false><<<gb(S_, NQ_, B_), 256, 0, stream>>>(
        adjb, h1t, t1b, nullptr, nullptr, 1.f, NQ_, S_, S_, S_, NQ_,
        (long)S_*S_, (long)NQ_*S_, (long)S_*NQ_);
    k_bgemm<0,0,false,4><<<gb(NTOK, 384, 4), 256, 0, stream>>>(
        t1b, gw1t, gbf, nullptr, gnn_b1, 1.f, 384, D_, D_, D_, 384, 0, 0, 0);
    k_t2b<true><<<dim3(12,32,2), 256, 0, stream>>>(gbf, gt, S_, 384, (long)S_*384, (long)S_*384);
    k_bgemm<0,1,false><<<gb(S_, 384, B_), 256, 0, stream>>>(
        adjb, gt, t2bv, nullptr, nullptr, 1.f, 384, S_, S_, S_, 384,
        (long)S_*S_, (long)384*S_, (long)S_*384);
    k_bgemm<0,2,false><<<gb(NTOK, D_, 1), 256, 0, stream>>>(
        t2bv, gw2t, h2b, h2f, gnn_b2, 1.f, D_, 384, 384, 384, D_, 0, 0, 0);

    // 5. attention: fused QKV -> flash attention -> WO -> add+LN
    k_bgemm<0,5,false><<<gb(NTOK, 3*D_, 1), 256, 0, stream>>>(
        h2b, wqkvt, Qh, nullptr, bqkv, 1.f, 3*D_, D_, D_, D_, 0, 0, 0, 0);
    k_fattn<<<dim3(S_/64, B_*H_), 256, 0, stream>>>(Qh, Kh, Vt, amask, ctxh);
    k_bgemm<1,0,false,2><<<gb(NTOK, D_, 2), 256, 0, stream>>>(
        ctxh, wqkvt + 3L*589824, ao, nullptr, bo, 1.f, D_, D_, D_, D_, D_, 0, 0, 0);
    k_addln<<<dim3(NTOK), dim3(256), 0, stream>>>(h2f, ao, ln1_g, ln1_b, hlnf, hlnb);

    // 6. FFN
    k_bgemm<0,1,true><<<gb(NTOK, 4*D_, 1), 256, 0, stream>>>(
        hlnb, fw1t, ff1b, nullptr, ff_b1, 1.f, 4*D_, D_, D_, D_, 4*D_, 0, 0, 0);
    k_bgemm<0,0,false,4><<<gb(NTOK, D_, 4), 256, 0, stream>>>(
        ff1b, fw2t, ao2, nullptr, ff_b2, 1.f, D_, 4*D_, 4*D_, 4*D_, D_, 0, 0, 0);
    k_addln<<<dim3(NTOK), dim3(256), 0, stream>>>(hlnf, ao2, ln2_g, ln2_b, nullptr, hfb);

    // 7. heads: parallel pool, vocab GEMM (256^2 ring-5 depth-3), parallel task
    k_pool<<<dim3(B_*16), dim3(256), 0, stream>>>(hfb, pooled);
    k_vgemm<<<dim3(NTOK/256, V_/256, 1), dim3(512), 163840, stream>>>(
        hfb, owt, (float*)d_out, out_b, V_, D_, D_, D_, V_);
    k_task<<<dim3(B_), dim3(256), 0, stream>>>(pooled, task_w, task_b, (float*)d_out);
}